// Round 2
// baseline (6305.679 us; speedup 1.0000x reference)
//
#include <hip/hip_runtime.h>

#define N_NODES 100000
#define N_EDGES 200000
#define N_GRAPHS 4000
#define F_IN 44
#define HDIM 256
#define EDIM 512
#define NLAYERS 4

// ---------------- zero fill (float4 granular; n4 = count/4) ----------------
__global__ void zero_kernel(float* __restrict__ p, size_t n4) {
    size_t i = (size_t)blockIdx.x * blockDim.x + threadIdx.x;
    const size_t stride = (size_t)gridDim.x * blockDim.x;
    const float4 z = make_float4(0.f, 0.f, 0.f, 0.f);
    for (; i < n4; i += stride) ((float4*)p)[i] = z;
}

// ---------------- atom MLP: h = relu(x @ W_atom + b_atom) ----------------
__global__ void atom_kernel(const float* __restrict__ x, const float* __restrict__ W,
                            const float* __restrict__ b, float* __restrict__ h) {
    __shared__ float xs[F_IN];
    const int i = blockIdx.x;
    const int j = threadIdx.x;              // 0..255 output channel
    if (j < F_IN) xs[j] = x[(size_t)i * F_IN + j];
    __syncthreads();
    float acc = b[j];
#pragma unroll
    for (int k = 0; k < F_IN; ++k) acc = fmaf(xs[k], W[(size_t)k * HDIM + j], acc);
    h[(size_t)i * HDIM + j] = fmaxf(acc, 0.f);
}

// ---------------- edge scatter-add: agg[dst] += h[src] ----------------
__global__ void scatter_kernel(const float* __restrict__ h, const int* __restrict__ src,
                               const int* __restrict__ dst, float* __restrict__ agg) {
    const int tid = threadIdx.x;
    const int e = blockIdx.x * 4 + (tid >> 6);
    const int t = tid & 63;
    const int s = src[e];
    const int d = dst[e];
    const float4 v = ((const float4*)(h + (size_t)s * HDIM))[t];
    float* ad = agg + (size_t)d * HDIM + (t << 2);
    atomicAdd(ad + 0, v.x);
    atomicAdd(ad + 1, v.y);
    atomicAdd(ad + 2, v.z);
    atomicAdd(ad + 3, v.w);
}

// ---------------- tiled fp32 GEMM: C = act((A [+ A2]) @ B + bias) ----------------
// BM=BN=64, BK=16, 256 threads, 4x4 per thread. A,B row-major. N,K multiples of 64/16.
template <bool ADD2, bool RELU>
__global__ void gemm_kernel(const float* __restrict__ A, const float* __restrict__ A2,
                            const float* __restrict__ B, const float* __restrict__ bias,
                            float* __restrict__ C, int M, int N, int K) {
    const int BM = 64, BN = 64, BK = 16;
    __shared__ float As[BK][BM + 4];   // row stride 68 floats = 272B (16B aligned)
    __shared__ float Bs[BK][BN];
    const int tid = threadIdx.x;
    const int tm = tid >> 4;           // 0..15
    const int tn = tid & 15;           // 0..15
    const int row0 = blockIdx.y * BM;
    const int col0 = blockIdx.x * BN;

    float acc[4][4] = {};

    const int ar = tid >> 2;           // 0..63 : A tile row
    const int ac = (tid & 3) << 2;     // 0,4,8,12 : A tile col (float4)
    const int br = tid >> 4;           // 0..15 : B tile row
    const int bc = (tid & 15) << 2;    // 0..60 : B tile col (float4)

    for (int k0 = 0; k0 < K; k0 += BK) {
        float4 av = make_float4(0.f, 0.f, 0.f, 0.f);
        if (row0 + ar < M) {
            const size_t aoff = (size_t)(row0 + ar) * K + k0 + ac;
            av = *(const float4*)(A + aoff);
            if (ADD2) {
                const float4 a2 = *(const float4*)(A2 + aoff);
                av.x += a2.x; av.y += a2.y; av.z += a2.z; av.w += a2.w;
            }
        }
        As[ac + 0][ar] = av.x;
        As[ac + 1][ar] = av.y;
        As[ac + 2][ar] = av.z;
        As[ac + 3][ar] = av.w;
        *(float4*)&Bs[br][bc] = *(const float4*)(B + (size_t)(k0 + br) * N + col0 + bc);
        __syncthreads();
#pragma unroll
        for (int k = 0; k < BK; ++k) {
            const float4 a4 = *(const float4*)&As[k][tm << 2];
            const float4 b4 = *(const float4*)&Bs[k][tn << 2];
            const float a[4] = {a4.x, a4.y, a4.z, a4.w};
            const float b[4] = {b4.x, b4.y, b4.z, b4.w};
#pragma unroll
            for (int i = 0; i < 4; ++i)
#pragma unroll
                for (int j = 0; j < 4; ++j) acc[i][j] = fmaf(a[i], b[j], acc[i][j]);
        }
        __syncthreads();
    }

#pragma unroll
    for (int i = 0; i < 4; ++i) {
        const int row = row0 + (tm << 2) + i;
        if (row < M) {
#pragma unroll
            for (int j = 0; j < 4; ++j) {
                const int col = col0 + (tn << 2) + j;
                float v = acc[i][j] + bias[col];
                if (RELU) v = fmaxf(v, 0.f);
                C[(size_t)row * N + col] = v;
            }
        }
    }
}

// ---------------- pool: sums[batch[i]] += h[i]; counts[batch[i]] += 1 ----------------
__global__ void pool_kernel(const float* __restrict__ h, const int* __restrict__ batch,
                            float* __restrict__ sums, float* __restrict__ counts) {
    const int tid = threadIdx.x;
    const int i = blockIdx.x * 4 + (tid >> 6);
    const int t = tid & 63;
    const int g = batch[i];
    const float4 v = ((const float4*)(h + (size_t)i * HDIM))[t];
    float* sp = sums + (size_t)g * HDIM + (t << 2);
    atomicAdd(sp + 0, v.x);
    atomicAdd(sp + 1, v.y);
    atomicAdd(sp + 2, v.z);
    atomicAdd(sp + 3, v.w);
    if (t == 0) atomicAdd(&counts[g], 1.0f);
}

__global__ void div_kernel(float* __restrict__ sums, const float* __restrict__ counts) {
    const int g = blockIdx.x;
    const int j = threadIdx.x;
    const float c = fmaxf(counts[g], 1.0f);
    sums[(size_t)g * HDIM + j] *= (1.0f / c);
}

extern "C" void kernel_launch(void* const* d_in, const int* in_sizes, int n_in,
                              void* d_out, int out_size, void* d_ws, size_t ws_size,
                              hipStream_t stream) {
    const float* x      = (const float*)d_in[0];
    const int*   eidx   = (const int*)d_in[1];
    const int*   batch  = (const int*)d_in[2];
    const float* W_atom = (const float*)d_in[3];
    const float* b_atom = (const float*)d_in[4];
    const float* W1     = (const float*)d_in[5];
    const float* b1     = (const float*)d_in[6];
    const float* W2     = (const float*)d_in[7];
    const float* b2     = (const float*)d_in[8];
    const float* Wf1    = (const float*)d_in[9];
    const float* bf1    = (const float*)d_in[10];
    const float* Wf2    = (const float*)d_in[11];
    const float* bf2    = (const float*)d_in[12];
    float* out = (float*)d_out;

    const int* src = eidx;             // edge_index[0]
    const int* dst = eidx + N_EDGES;   // edge_index[1]

    const size_t NH = (size_t)N_NODES * HDIM;      // 25.6M floats (102.4 MB)
    const size_t GH = (size_t)N_GRAPHS * HDIM;     // 1.024M floats

    // ---- adaptive workspace layout: h | agg | rest ----
    float* h    = (float*)d_ws;
    float* agg  = h + NH;
    float* rest = agg + NH;
    const size_t total_floats = ws_size / sizeof(float);
    const size_t avail = (total_floats > 2 * NH) ? (total_floats - 2 * NH) : 0;

    // z2 chunk rows sized to what's left of the workspace
    long chunk = (long)(avail / (2 * HDIM));
    if (chunk >= N_NODES) chunk = N_NODES;
    else chunk &= ~63L;
    if (chunk < 64) chunk = 64;        // ws too small; best effort

    float* z2buf = rest;                                // during layers
    float* sums  = rest;                                // after layers (z2 dead)
    float* cnts  = sums + GH;
    float* hg1   = cnts + 4096;

    // 1. atom MLP
    atom_kernel<<<N_NODES, 256, 0, stream>>>(x, W_atom, b_atom, h);

    // 2. GIN layers (z2 chunked; h updated in place per chunk)
    for (int l = 0; l < NLAYERS; ++l) {
        zero_kernel<<<2048, 256, 0, stream>>>(agg, NH / 4);
        scatter_kernel<<<N_EDGES / 4, 256, 0, stream>>>(h, src, dst, agg);
        for (long r0 = 0; r0 < N_NODES; r0 += chunk) {
            const int mc = (int)((N_NODES - r0 < chunk) ? (N_NODES - r0) : chunk);
            // z2buf = relu((h + agg)[r0:r0+mc] @ W1[l] + b1[l])   [mc, 512]
            gemm_kernel<true, true><<<dim3(2 * HDIM / 64, (mc + 63) / 64), 256, 0, stream>>>(
                h + r0 * HDIM, agg + r0 * HDIM,
                W1 + (size_t)l * HDIM * 2 * HDIM, b1 + (size_t)l * 2 * HDIM,
                z2buf, mc, 2 * HDIM, HDIM);
            // h[r0:r0+mc] = relu(z2buf @ W2[l] + b2[l])           [mc, 256]
            gemm_kernel<false, true><<<dim3(HDIM / 64, (mc + 63) / 64), 256, 0, stream>>>(
                z2buf, nullptr,
                W2 + (size_t)l * 2 * HDIM * HDIM, b2 + (size_t)l * HDIM,
                h + r0 * HDIM, mc, HDIM, 2 * HDIM);
        }
    }

    // 3. global mean pool (sums+cnts live in the dead z2 region)
    zero_kernel<<<1024, 256, 0, stream>>>(sums, (GH + 4096) / 4);
    pool_kernel<<<N_NODES / 4, 256, 0, stream>>>(h, batch, sums, cnts);
    div_kernel<<<N_GRAPHS, HDIM, 0, stream>>>(sums, cnts);

    // 4. head: hg1 = relu(sums @ Wf1 + bf1); out = hg1 @ Wf2 + bf2
    gemm_kernel<false, true><<<dim3(HDIM / 64, (N_GRAPHS + 63) / 64), 256, 0, stream>>>(
        sums, nullptr, Wf1, bf1, hg1, N_GRAPHS, HDIM, HDIM);
    gemm_kernel<false, false><<<dim3(EDIM / 64, (N_GRAPHS + 63) / 64), 256, 0, stream>>>(
        hg1, nullptr, Wf2, bf2, out, N_GRAPHS, EDIM, HDIM);
}

// Round 3
// 3555.502 us; speedup vs baseline: 1.7735x; 1.7735x over previous
//
#include <hip/hip_runtime.h>

#define N_NODES 100000
#define N_EDGES 200000
#define N_GRAPHS 4000
#define F_IN 44
#define HDIM 256
#define EDIM 512
#define NLAYERS 4

// ---------------- zero fill (float4 granular; n4 = count/4) ----------------
__global__ void zero_kernel(float* __restrict__ p, size_t n4) {
    size_t i = (size_t)blockIdx.x * blockDim.x + threadIdx.x;
    const size_t stride = (size_t)gridDim.x * blockDim.x;
    const float4 z = make_float4(0.f, 0.f, 0.f, 0.f);
    for (; i < n4; i += stride) ((float4*)p)[i] = z;
}

// ---------------- atom MLP: h = relu(x @ W_atom + b_atom) ----------------
__global__ void atom_kernel(const float* __restrict__ x, const float* __restrict__ W,
                            const float* __restrict__ b, float* __restrict__ h) {
    __shared__ float xs[F_IN];
    const int i = blockIdx.x;
    const int j = threadIdx.x;
    if (j < F_IN) xs[j] = x[(size_t)i * F_IN + j];
    __syncthreads();
    float acc = b[j];
#pragma unroll
    for (int k = 0; k < F_IN; ++k) acc = fmaf(xs[k], W[(size_t)k * HDIM + j], acc);
    h[(size_t)i * HDIM + j] = fmaxf(acc, 0.f);
}

// ---------------- CSR build: hist -> scan -> fill ----------------
__global__ void hist_kernel(const int* __restrict__ dst, int* __restrict__ deg) {
    const int e = blockIdx.x * 256 + threadIdx.x;
    if (e < N_EDGES) atomicAdd(&deg[dst[e]], 1);
}

__global__ void scan1_kernel(const int* __restrict__ deg, int* __restrict__ row_ptr,
                             int* __restrict__ blk) {
    __shared__ int s[256];
    const int i = blockIdx.x * 256 + threadIdx.x;
    s[threadIdx.x] = (i < N_NODES) ? deg[i] : 0;
    __syncthreads();
    for (int off = 1; off < 256; off <<= 1) {
        int t = (threadIdx.x >= off) ? s[threadIdx.x - off] : 0;
        __syncthreads();
        s[threadIdx.x] += t;
        __syncthreads();
    }
    if (i < N_NODES) row_ptr[i + 1] = s[threadIdx.x];   // inclusive, pre-offset
    if (threadIdx.x == 255) blk[blockIdx.x] = s[255];
}

__global__ void scan2_kernel(int* __restrict__ blk, int nb) {
    if (threadIdx.x == 0 && blockIdx.x == 0) {
        int run = 0;
        for (int b = 0; b < nb; ++b) { const int t = blk[b]; blk[b] = run; run += t; }
    }
}

__global__ void scan3_kernel(int* __restrict__ row_ptr, const int* __restrict__ blk) {
    const int i = blockIdx.x * 256 + threadIdx.x;
    if (i < N_NODES) row_ptr[i + 1] += blk[i >> 8];
    if (i == 0) row_ptr[0] = 0;
}

__global__ void cursor_kernel(const int* __restrict__ row_ptr, int* __restrict__ cursor) {
    const int i = blockIdx.x * 256 + threadIdx.x;
    if (i < N_NODES) cursor[i] = row_ptr[i];
}

__global__ void fill_kernel(const int* __restrict__ src, const int* __restrict__ dst,
                            int* __restrict__ cursor, int* __restrict__ eids) {
    const int e = blockIdx.x * 256 + threadIdx.x;
    if (e < N_EDGES) {
        const int pos = atomicAdd(&cursor[dst[e]], 1);
        eids[pos] = src[e];
    }
}

// ---------------- gather: z[i] = h[i] + sum_{j->i} h[j]  (GIN, eps=0) ----------------
__global__ void gather_kernel(const float* __restrict__ h, const int* __restrict__ row_ptr,
                              const int* __restrict__ eids, float* __restrict__ z) {
    const int tid = threadIdx.x;
    const int n = blockIdx.x * 4 + (tid >> 6);
    const int t = tid & 63;
    const float4* h4 = (const float4*)h;
    float4 acc = h4[(size_t)n * 64 + t];          // eps=0 self term
    const int s = row_ptr[n], e = row_ptr[n + 1];
    for (int i = s; i < e; ++i) {
        const int sr = eids[i];
        const float4 v = h4[(size_t)sr * 64 + t];
        acc.x += v.x; acc.y += v.y; acc.z += v.z; acc.w += v.w;
    }
    ((float4*)z)[(size_t)n * 64 + t] = acc;
}

// ---------------- tiled fp32 GEMM: C = act(A @ B + bias), 128x128x16, 8x8/thread ----
template <bool RELU>
__global__ __launch_bounds__(256)
void gemm_kernel(const float* __restrict__ A, const float* __restrict__ B,
                 const float* __restrict__ bias, float* __restrict__ C,
                 int M, int N, int K) {
    const int BM = 128, BN = 128, BK = 16;
    __shared__ float As[BK][BM + 4];
    __shared__ float Bs[BK][BN + 4];
    const int tid = threadIdx.x;
    const int tm = tid >> 4;           // 0..15
    const int tn = tid & 15;           // 0..15
    const int row0 = blockIdx.y * BM;
    const int col0 = blockIdx.x * BN;

    float acc[8][8] = {};

    const int ar = tid >> 2;           // 0..63 : A tile row (x2)
    const int ac = (tid & 3) << 2;     // 0,4,8,12
    const int br = tid >> 5;           // 0..7  : B tile row (x2)
    const int bc = (tid & 31) << 2;    // 0..124

    for (int k0 = 0; k0 < K; k0 += BK) {
#pragma unroll
        for (int ii = 0; ii < 2; ++ii) {
            const int r = ar + ii * 64;
            float4 av = make_float4(0.f, 0.f, 0.f, 0.f);
            if (row0 + r < M)
                av = *(const float4*)(A + (size_t)(row0 + r) * K + k0 + ac);
            As[ac + 0][r] = av.x;
            As[ac + 1][r] = av.y;
            As[ac + 2][r] = av.z;
            As[ac + 3][r] = av.w;
        }
#pragma unroll
        for (int ii = 0; ii < 2; ++ii) {
            const int r = br + ii * 8;
            *(float4*)&Bs[r][bc] = *(const float4*)(B + (size_t)(k0 + r) * N + col0 + bc);
        }
        __syncthreads();
#pragma unroll
        for (int k = 0; k < BK; ++k) {
            float a[8], b[8];
            *(float4*)&a[0] = *(const float4*)&As[k][tm * 8];
            *(float4*)&a[4] = *(const float4*)&As[k][tm * 8 + 4];
            *(float4*)&b[0] = *(const float4*)&Bs[k][tn * 8];
            *(float4*)&b[4] = *(const float4*)&Bs[k][tn * 8 + 4];
#pragma unroll
            for (int i = 0; i < 8; ++i)
#pragma unroll
                for (int j = 0; j < 8; ++j) acc[i][j] = fmaf(a[i], b[j], acc[i][j]);
        }
        __syncthreads();
    }

#pragma unroll
    for (int i = 0; i < 8; ++i) {
        const int row = row0 + tm * 8 + i;
        if (row < M) {
#pragma unroll
            for (int j = 0; j < 8; j += 4) {
                const int col = col0 + tn * 8 + j;
                float4 v;
                v.x = acc[i][j + 0] + bias[col + 0];
                v.y = acc[i][j + 1] + bias[col + 1];
                v.z = acc[i][j + 2] + bias[col + 2];
                v.w = acc[i][j + 3] + bias[col + 3];
                if (RELU) {
                    v.x = fmaxf(v.x, 0.f); v.y = fmaxf(v.y, 0.f);
                    v.z = fmaxf(v.z, 0.f); v.w = fmaxf(v.w, 0.f);
                }
                *(float4*)(C + (size_t)row * N + col) = v;
            }
        }
    }
}

// ---------------- pool: sorted-batch segment mean, one block per graph ----------------
__global__ void pool_kernel(const float* __restrict__ h, const int* __restrict__ batch,
                            float* __restrict__ outp) {
    __shared__ int sse[2];
    const int g = blockIdx.x;
    if (threadIdx.x < 2) {
        const int target = g + threadIdx.x;   // lower_bound(batch, target)
        int lo = 0, hi = N_NODES;
        while (lo < hi) {
            const int mid = (lo + hi) >> 1;
            if (batch[mid] < target) lo = mid + 1; else hi = mid;
        }
        sse[threadIdx.x] = lo;
    }
    __syncthreads();
    const int s = sse[0], e = sse[1];
    const int j = threadIdx.x;
    float acc = 0.f;
    for (int n = s; n < e; ++n) acc += h[(size_t)n * HDIM + j];
    const float inv = (e > s) ? 1.f / (float)(e - s) : 1.f;
    outp[(size_t)g * HDIM + j] = acc * inv;
}

extern "C" void kernel_launch(void* const* d_in, const int* in_sizes, int n_in,
                              void* d_out, int out_size, void* d_ws, size_t ws_size,
                              hipStream_t stream) {
    const float* x      = (const float*)d_in[0];
    const int*   eidx   = (const int*)d_in[1];
    const int*   batch  = (const int*)d_in[2];
    const float* W_atom = (const float*)d_in[3];
    const float* b_atom = (const float*)d_in[4];
    const float* W1     = (const float*)d_in[5];
    const float* b1     = (const float*)d_in[6];
    const float* W2     = (const float*)d_in[7];
    const float* b2     = (const float*)d_in[8];
    const float* Wf1    = (const float*)d_in[9];
    const float* bf1    = (const float*)d_in[10];
    const float* Wf2    = (const float*)d_in[11];
    const float* bf2    = (const float*)d_in[12];
    float* out = (float*)d_out;

    const int* src = eidx;             // edge_index[0]
    const int* dst = eidx + N_EDGES;   // edge_index[1]

    const size_t NH = (size_t)N_NODES * HDIM;      // 25.6M floats
    const size_t GH = (size_t)N_GRAPHS * HDIM;

    // ---- workspace layout: h | z (gather out) | CSR ints | rest ----
    float* h   = (float*)d_ws;
    float* zin = h + NH;               // z = h + agg (gather output, GEMM1 input)
    int*   deg     = (int*)(zin + NH);
    int*   row_ptr = deg + N_NODES;            // N+1
    int*   cursor  = row_ptr + N_NODES + 1;
    int*   eids    = cursor + N_NODES;
    int*   blk     = eids + N_EDGES;           // 512 slots
    float* rest    = (float*)(blk + 512);

    const size_t used = (size_t)(rest - (float*)d_ws);
    const size_t total_floats = ws_size / sizeof(float);
    const size_t avail = (total_floats > used) ? (total_floats - used) : 0;

    long chunk = (long)(avail / (2 * HDIM));
    if (chunk >= N_NODES) chunk = N_NODES;
    else chunk &= ~127L;
    if (chunk < 128) chunk = 128;

    float* z2buf = rest;                       // during layers
    float* sums  = rest;                       // after layers (z2 dead)
    float* hg1   = sums + GH;

    const int nb = (N_NODES + 255) / 256;      // scan blocks (391)

    // 1. atom MLP
    atom_kernel<<<N_NODES, 256, 0, stream>>>(x, W_atom, b_atom, h);

    // 2. CSR build (once; reused all layers)
    zero_kernel<<<128, 256, 0, stream>>>((float*)deg, N_NODES / 4);
    hist_kernel<<<(N_EDGES + 255) / 256, 256, 0, stream>>>(dst, deg);
    scan1_kernel<<<nb, 256, 0, stream>>>(deg, row_ptr, blk);
    scan2_kernel<<<1, 64, 0, stream>>>(blk, nb);
    scan3_kernel<<<nb, 256, 0, stream>>>(row_ptr, blk);
    cursor_kernel<<<nb, 256, 0, stream>>>(row_ptr, cursor);
    fill_kernel<<<(N_EDGES + 255) / 256, 256, 0, stream>>>(src, dst, cursor, eids);

    // 3. GIN layers
    for (int l = 0; l < NLAYERS; ++l) {
        gather_kernel<<<N_NODES / 4, 256, 0, stream>>>(h, row_ptr, eids, zin);
        for (long r0 = 0; r0 < N_NODES; r0 += chunk) {
            const int mc = (int)((N_NODES - r0 < chunk) ? (N_NODES - r0) : chunk);
            // z2 = relu(z @ W1[l] + b1[l])   [mc, 512]
            gemm_kernel<true><<<dim3(2 * HDIM / 128, (mc + 127) / 128), 256, 0, stream>>>(
                zin + r0 * HDIM, W1 + (size_t)l * HDIM * 2 * HDIM, b1 + (size_t)l * 2 * HDIM,
                z2buf, mc, 2 * HDIM, HDIM);
            // h = relu(z2 @ W2[l] + b2[l])   [mc, 256]
            gemm_kernel<true><<<dim3(HDIM / 128, (mc + 127) / 128), 256, 0, stream>>>(
                z2buf, W2 + (size_t)l * 2 * HDIM * HDIM, b2 + (size_t)l * HDIM,
                h + r0 * HDIM, mc, HDIM, 2 * HDIM);
        }
    }

    // 4. global mean pool (sorted batch -> segment mean)
    pool_kernel<<<N_GRAPHS, HDIM, 0, stream>>>(h, batch, sums);

    // 5. head
    gemm_kernel<true><<<dim3(HDIM / 128, (N_GRAPHS + 127) / 128), 256, 0, stream>>>(
        sums, Wf1, bf1, hg1, N_GRAPHS, HDIM, HDIM);
    gemm_kernel<false><<<dim3(EDIM / 128, (N_GRAPHS + 127) / 128), 256, 0, stream>>>(
        hg1, Wf2, bf2, out, N_GRAPHS, EDIM, HDIM);
}

// Round 4
// 1952.856 us; speedup vs baseline: 3.2290x; 1.8207x over previous
//
#include <hip/hip_runtime.h>

#define N_NODES 100000
#define N_EDGES 200000
#define N_GRAPHS 4000
#define F_IN 44
#define HDIM 256
#define EDIM 512
#define NLAYERS 4

typedef float floatx4 __attribute__((ext_vector_type(4)));
typedef short bhalf8 __attribute__((ext_vector_type(8)));

__device__ __forceinline__ unsigned short f2bf(float f) {
    unsigned int u = __float_as_uint(f);
    u += 0x7FFFu + ((u >> 16) & 1u);          // RNE
    return (unsigned short)(u >> 16);
}
__device__ __forceinline__ float bf2f(unsigned short s) {
    return __uint_as_float(((unsigned int)s) << 16);
}

// ---------------- zero fill ----------------
__global__ void zero_kernel(float* __restrict__ p, size_t n4) {
    size_t i = (size_t)blockIdx.x * blockDim.x + threadIdx.x;
    const size_t stride = (size_t)gridDim.x * blockDim.x;
    const float4 z = make_float4(0.f, 0.f, 0.f, 0.f);
    for (; i < n4; i += stride) ((float4*)p)[i] = z;
}

// ---------------- atom MLP: h = relu(x @ W_atom + b_atom), 8 nodes/block ----------------
__global__ __launch_bounds__(256) void atom_kernel(const float* __restrict__ x,
                                                   const float* __restrict__ W,
                                                   const float* __restrict__ b,
                                                   float* __restrict__ h) {
    __shared__ float xs[8][F_IN];
    const int n0 = blockIdx.x * 8;
    const int t = threadIdx.x;
    for (int i = t; i < 8 * F_IN; i += 256) {
        const int n = i / F_IN, k = i % F_IN;
        xs[n][k] = x[(size_t)(n0 + n) * F_IN + k];
    }
    __syncthreads();
    const int j = t;
    float acc[8];
    const float bj = b[j];
#pragma unroll
    for (int n = 0; n < 8; ++n) acc[n] = bj;
    for (int k = 0; k < F_IN; ++k) {
        const float w = W[k * HDIM + j];
#pragma unroll
        for (int n = 0; n < 8; ++n) acc[n] = fmaf(xs[n][k], w, acc[n]);
    }
#pragma unroll
    for (int n = 0; n < 8; ++n) h[(size_t)(n0 + n) * HDIM + j] = fmaxf(acc[n], 0.f);
}

// ---------------- CSR build ----------------
__global__ void hist_kernel(const int* __restrict__ dst, int* __restrict__ deg) {
    const int e = blockIdx.x * 256 + threadIdx.x;
    if (e < N_EDGES) atomicAdd(&deg[dst[e]], 1);
}

__global__ void scan1_kernel(const int* __restrict__ deg, int* __restrict__ row_ptr,
                             int* __restrict__ blk) {
    __shared__ int s[256];
    const int i = blockIdx.x * 256 + threadIdx.x;
    s[threadIdx.x] = (i < N_NODES) ? deg[i] : 0;
    __syncthreads();
    for (int off = 1; off < 256; off <<= 1) {
        int t = (threadIdx.x >= off) ? s[threadIdx.x - off] : 0;
        __syncthreads();
        s[threadIdx.x] += t;
        __syncthreads();
    }
    if (i < N_NODES) row_ptr[i + 1] = s[threadIdx.x];
    if (threadIdx.x == 255) blk[blockIdx.x] = s[255];
}

__global__ void scan2_kernel(int* __restrict__ blk, int nb) {
    if (threadIdx.x == 0 && blockIdx.x == 0) {
        int run = 0;
        for (int b = 0; b < nb; ++b) { const int t = blk[b]; blk[b] = run; run += t; }
    }
}

__global__ void scan3_kernel(int* __restrict__ row_ptr, const int* __restrict__ blk) {
    const int i = blockIdx.x * 256 + threadIdx.x;
    if (i < N_NODES) row_ptr[i + 1] += blk[i >> 8];
    if (i == 0) row_ptr[0] = 0;
}

__global__ void cursor_kernel(const int* __restrict__ row_ptr, int* __restrict__ cursor) {
    const int i = blockIdx.x * 256 + threadIdx.x;
    if (i < N_NODES) cursor[i] = row_ptr[i];
}

__global__ void fill_kernel(const int* __restrict__ src, const int* __restrict__ dst,
                            int* __restrict__ cursor, int* __restrict__ eids) {
    const int e = blockIdx.x * 256 + threadIdx.x;
    if (e < N_EDGES) {
        const int pos = atomicAdd(&cursor[dst[e]], 1);
        eids[pos] = src[e];
    }
}

// ---------------- gather: z = h + sum_neigh h, split-write bf16 hi/lo ----------------
__global__ void gather_kernel(const float* __restrict__ h, const int* __restrict__ row_ptr,
                              const int* __restrict__ eids,
                              unsigned short* __restrict__ zhi,
                              unsigned short* __restrict__ zlo) {
    const int tid = threadIdx.x;
    const int n = blockIdx.x * 4 + (tid >> 6);
    const int t = tid & 63;
    const float4* h4 = (const float4*)h;
    float4 acc = h4[(size_t)n * 64 + t];
    const int s = row_ptr[n], e = row_ptr[n + 1];
    for (int i = s; i < e; ++i) {
        const float4 v = h4[(size_t)eids[i] * 64 + t];
        acc.x += v.x; acc.y += v.y; acc.z += v.z; acc.w += v.w;
    }
    ushort4 hi, lo;
    hi.x = f2bf(acc.x); lo.x = f2bf(acc.x - bf2f(hi.x));
    hi.y = f2bf(acc.y); lo.y = f2bf(acc.y - bf2f(hi.y));
    hi.z = f2bf(acc.z); lo.z = f2bf(acc.z - bf2f(hi.z));
    hi.w = f2bf(acc.w); lo.w = f2bf(acc.w - bf2f(hi.w));
    *(ushort4*)(zhi + (size_t)n * HDIM + t * 4) = hi;
    *(ushort4*)(zlo + (size_t)n * HDIM + t * 4) = lo;
}

// ---------------- weight prep: W[K][N] fp32 -> WT_hi/WT_lo [N][K] bf16 ----------------
__global__ void wprep_kernel(const float* __restrict__ W, int K, int N,
                             unsigned short* __restrict__ Thi,
                             unsigned short* __restrict__ Tlo) {
    const int idx = blockIdx.x * 256 + threadIdx.x;
    if (idx < K * N) {
        const int k = idx / N, n = idx % N;
        const float v = W[idx];
        const unsigned short hh = f2bf(v);
        Thi[(size_t)n * K + k] = hh;
        Tlo[(size_t)n * K + k] = f2bf(v - bf2f(hh));
    }
}

// ---------------- MFMA GEMM: C = act(A @ B + bias), bf16 hi/lo split, 3-pass ----------
// A as (Ahi,Alo) [M][K] bf16 row-major; B as (BThi,BTlo) [N][K] bf16 (pre-transposed).
// 128x128 tile, BK=32, 256 thr = 4 waves (2x2 of 64x64), 16x16x32 MFMA.
// OUT: 0 = fp32, 1 = fp32+relu, 2 = bf16 hi/lo split + relu
template <int OUT>
__global__ __launch_bounds__(256)
void gemm_mfma(const unsigned short* __restrict__ Ahi, const unsigned short* __restrict__ Alo,
               const unsigned short* __restrict__ BThi, const unsigned short* __restrict__ BTlo,
               const float* __restrict__ bias,
               float* __restrict__ C, unsigned short* __restrict__ Chi,
               unsigned short* __restrict__ Clo, int M, int N, int K) {
    // rows padded to 40 ushorts = 80 B -> 2-way max bank aliasing on b128 reads (free)
    __shared__ __align__(16) unsigned short Ah[128][40];
    __shared__ __align__(16) unsigned short Al[128][40];
    __shared__ __align__(16) unsigned short Bh[128][40];
    __shared__ __align__(16) unsigned short Bl[128][40];

    const int tid = threadIdx.x;
    const int row0 = blockIdx.y * 128;
    const int col0 = blockIdx.x * 128;

    // staging: thread -> (row, 16-elem half of the 32-wide K-slice)
    const int srow = tid >> 1;
    const int sc0 = (tid & 1) * 16;
    const int agrow = row0 + srow;
    const bool aval = agrow < M;
    const unsigned short* pAh = Ahi + (size_t)(aval ? agrow : 0) * K + sc0;
    const unsigned short* pAl = Alo + (size_t)(aval ? agrow : 0) * K + sc0;
    const unsigned short* pBh = BThi + (size_t)(col0 + srow) * K + sc0;
    const unsigned short* pBl = BTlo + (size_t)(col0 + srow) * K + sc0;

    const int wv = tid >> 6;
    const int wr = wv >> 1, wc = wv & 1;
    const int lane = tid & 63;
    const int lr = lane & 15;
    const int kb = (lane >> 4) * 8;   // fragment k-chunk (8 bf16 = 16 B)

    floatx4 acc[4][4];
#pragma unroll
    for (int m = 0; m < 4; ++m)
#pragma unroll
        for (int n = 0; n < 4; ++n) acc[m][n] = (floatx4){0.f, 0.f, 0.f, 0.f};

    const uint4 zz = make_uint4(0u, 0u, 0u, 0u);
    uint4 ra0, ra1, rb0, rb1, rc0, rc1, rd0, rd1;

    // prefetch K-tile 0
    ra0 = aval ? *(const uint4*)(pAh + 0) : zz;
    ra1 = aval ? *(const uint4*)(pAh + 8) : zz;
    rb0 = aval ? *(const uint4*)(pAl + 0) : zz;
    rb1 = aval ? *(const uint4*)(pAl + 8) : zz;
    rc0 = *(const uint4*)(pBh + 0);
    rc1 = *(const uint4*)(pBh + 8);
    rd0 = *(const uint4*)(pBl + 0);
    rd1 = *(const uint4*)(pBl + 8);

    const int NT = K >> 5;
    for (int t = 0; t < NT; ++t) {
        __syncthreads();
        *(uint4*)&Ah[srow][sc0 + 0] = ra0;
        *(uint4*)&Ah[srow][sc0 + 8] = ra1;
        *(uint4*)&Al[srow][sc0 + 0] = rb0;
        *(uint4*)&Al[srow][sc0 + 8] = rb1;
        *(uint4*)&Bh[srow][sc0 + 0] = rc0;
        *(uint4*)&Bh[srow][sc0 + 8] = rc1;
        *(uint4*)&Bl[srow][sc0 + 0] = rd0;
        *(uint4*)&Bl[srow][sc0 + 8] = rd1;
        if (t + 1 < NT) {   // prefetch next tile; drains during MFMA phase
            const int ko = (t + 1) << 5;
            ra0 = aval ? *(const uint4*)(pAh + ko + 0) : zz;
            ra1 = aval ? *(const uint4*)(pAh + ko + 8) : zz;
            rb0 = aval ? *(const uint4*)(pAl + ko + 0) : zz;
            rb1 = aval ? *(const uint4*)(pAl + ko + 8) : zz;
            rc0 = *(const uint4*)(pBh + ko + 0);
            rc1 = *(const uint4*)(pBh + ko + 8);
            rd0 = *(const uint4*)(pBl + ko + 0);
            rd1 = *(const uint4*)(pBl + ko + 8);
        }
        __syncthreads();

        bhalf8 fah[4], fal[4], fbh[4], fbl[4];
#pragma unroll
        for (int m = 0; m < 4; ++m) {
            const int r = wr * 64 + m * 16 + lr;
            fah[m] = *(const bhalf8*)&Ah[r][kb];
            fal[m] = *(const bhalf8*)&Al[r][kb];
        }
#pragma unroll
        for (int n = 0; n < 4; ++n) {
            const int c = wc * 64 + n * 16 + lr;
            fbh[n] = *(const bhalf8*)&Bh[c][kb];
            fbl[n] = *(const bhalf8*)&Bl[c][kb];
        }
#pragma unroll
        for (int m = 0; m < 4; ++m)
#pragma unroll
            for (int n = 0; n < 4; ++n) {
                acc[m][n] = __builtin_amdgcn_mfma_f32_16x16x32_bf16(fah[m], fbh[n], acc[m][n], 0, 0, 0);
                acc[m][n] = __builtin_amdgcn_mfma_f32_16x16x32_bf16(fal[m], fbh[n], acc[m][n], 0, 0, 0);
                acc[m][n] = __builtin_amdgcn_mfma_f32_16x16x32_bf16(fah[m], fbl[n], acc[m][n], 0, 0, 0);
            }
    }

    // epilogue: C/D layout col = lane&15, row = (lane>>4)*4 + reg
    const int rgrp = (lane >> 4) * 4;
#pragma unroll
    for (int n = 0; n < 4; ++n) {
        const int col = col0 + wc * 64 + n * 16 + lr;
        const float bv = bias[col];
#pragma unroll
        for (int m = 0; m < 4; ++m) {
            const int rw = row0 + wr * 64 + m * 16 + rgrp;
#pragma unroll
            for (int j = 0; j < 4; ++j) {
                const int row = rw + j;
                if (row < M) {
                    float v = acc[m][n][j] + bv;
                    if (OUT >= 1) v = fmaxf(v, 0.f);
                    if (OUT == 2) {
                        const unsigned short hh = f2bf(v);
                        Chi[(size_t)row * N + col] = hh;
                        Clo[(size_t)row * N + col] = f2bf(v - bf2f(hh));
                    } else {
                        C[(size_t)row * N + col] = v;
                    }
                }
            }
        }
    }
}

// ---------------- pool: sorted-batch segment mean -> bf16 hi/lo ----------------
__global__ void pool_kernel(const float* __restrict__ h, const int* __restrict__ batch,
                            unsigned short* __restrict__ ghi, unsigned short* __restrict__ glo) {
    __shared__ int sse[2];
    const int g = blockIdx.x;
    if (threadIdx.x < 2) {
        const int target = g + threadIdx.x;
        int lo = 0, hi = N_NODES;
        while (lo < hi) {
            const int mid = (lo + hi) >> 1;
            if (batch[mid] < target) lo = mid + 1; else hi = mid;
        }
        sse[threadIdx.x] = lo;
    }
    __syncthreads();
    const int s = sse[0], e = sse[1];
    const int j = threadIdx.x;
    float acc = 0.f;
    for (int n = s; n < e; ++n) acc += h[(size_t)n * HDIM + j];
    const float v = acc * ((e > s) ? 1.f / (float)(e - s) : 1.f);
    const unsigned short hh = f2bf(v);
    ghi[(size_t)g * HDIM + j] = hh;
    glo[(size_t)g * HDIM + j] = f2bf(v - bf2f(hh));
}

extern "C" void kernel_launch(void* const* d_in, const int* in_sizes, int n_in,
                              void* d_out, int out_size, void* d_ws, size_t ws_size,
                              hipStream_t stream) {
    const float* x      = (const float*)d_in[0];
    const int*   eidx   = (const int*)d_in[1];
    const int*   batch  = (const int*)d_in[2];
    const float* W_atom = (const float*)d_in[3];
    const float* b_atom = (const float*)d_in[4];
    const float* W1     = (const float*)d_in[5];
    const float* b1     = (const float*)d_in[6];
    const float* W2     = (const float*)d_in[7];
    const float* b2     = (const float*)d_in[8];
    const float* Wf1    = (const float*)d_in[9];
    const float* bf1    = (const float*)d_in[10];
    const float* Wf2    = (const float*)d_in[11];
    const float* bf2    = (const float*)d_in[12];
    float* out = (float*)d_out;

    const int* src = eidx;
    const int* dst = eidx + N_EDGES;

    const size_t NH = (size_t)N_NODES * HDIM;           // 25.6M elems
    const int WSZ = HDIM * 2 * HDIM;                    // 131072 elems per layer weight

    // ---- workspace layout ----
    char* base = (char*)d_ws;
    size_t off = 0;
    float* h = (float*)(base + off);              off += NH * 4;
    unsigned short* zin_hi = (unsigned short*)(base + off); off += NH * 2;
    unsigned short* zin_lo = (unsigned short*)(base + off); off += NH * 2;
    int* deg     = (int*)(base + off);            off += (size_t)N_NODES * 4;
    int* row_ptr = (int*)(base + off);            off += (size_t)(N_NODES + 1) * 4;
    int* cursor  = (int*)(base + off);            off += (size_t)N_NODES * 4;
    int* eids    = (int*)(base + off);            off += (size_t)N_EDGES * 4;
    int* blk     = (int*)(base + off);            off += 512 * 4;
    off = (off + 255) & ~(size_t)255;
    unsigned short* w1thi = (unsigned short*)(base + off); off += (size_t)NLAYERS * WSZ * 2;
    unsigned short* w1tlo = (unsigned short*)(base + off); off += (size_t)NLAYERS * WSZ * 2;
    unsigned short* w2thi = (unsigned short*)(base + off); off += (size_t)NLAYERS * WSZ * 2;
    unsigned short* w2tlo = (unsigned short*)(base + off); off += (size_t)NLAYERS * WSZ * 2;
    unsigned short* wf1thi = (unsigned short*)(base + off); off += (size_t)HDIM * HDIM * 2;
    unsigned short* wf1tlo = (unsigned short*)(base + off); off += (size_t)HDIM * HDIM * 2;
    unsigned short* wf2thi = (unsigned short*)(base + off); off += (size_t)HDIM * EDIM * 2;
    unsigned short* wf2tlo = (unsigned short*)(base + off); off += (size_t)HDIM * EDIM * 2;
    off = (off + 255) & ~(size_t)255;

    const size_t avail = (ws_size > off) ? ws_size - off : 0;
    long chunk = (long)(avail / ((size_t)EDIM * 2 * 2));    // bytes per z2 row (hi+lo bf16)
    if (chunk >= N_NODES) chunk = N_NODES;
    else chunk &= ~127L;
    if (chunk < 128) chunk = 128;
    unsigned short* z2hi = (unsigned short*)(base + off);
    unsigned short* z2lo = z2hi + (size_t)chunk * EDIM;

    // head buffers overlap the (dead-after-layers) zin region
    const size_t GH = (size_t)N_GRAPHS * HDIM;
    unsigned short* hg_hi  = zin_hi;
    unsigned short* hg_lo  = zin_hi + GH;
    unsigned short* hg1_hi = zin_hi + 2 * GH;
    unsigned short* hg1_lo = zin_hi + 3 * GH;

    const int nb = (N_NODES + 255) / 256;

    // 1. atom MLP
    atom_kernel<<<N_NODES / 8, 256, 0, stream>>>(x, W_atom, b_atom, h);

    // 2. CSR build
    zero_kernel<<<128, 256, 0, stream>>>((float*)deg, N_NODES / 4);
    hist_kernel<<<(N_EDGES + 255) / 256, 256, 0, stream>>>(dst, deg);
    scan1_kernel<<<nb, 256, 0, stream>>>(deg, row_ptr, blk);
    scan2_kernel<<<1, 64, 0, stream>>>(blk, nb);
    scan3_kernel<<<nb, 256, 0, stream>>>(row_ptr, blk);
    cursor_kernel<<<nb, 256, 0, stream>>>(row_ptr, cursor);
    fill_kernel<<<(N_EDGES + 255) / 256, 256, 0, stream>>>(src, dst, cursor, eids);

    // 3. weight transpose + bf16 split
    for (int l = 0; l < NLAYERS; ++l) {
        wprep_kernel<<<(WSZ + 255) / 256, 256, 0, stream>>>(
            W1 + (size_t)l * WSZ, HDIM, 2 * HDIM, w1thi + (size_t)l * WSZ, w1tlo + (size_t)l * WSZ);
        wprep_kernel<<<(WSZ + 255) / 256, 256, 0, stream>>>(
            W2 + (size_t)l * WSZ, 2 * HDIM, HDIM, w2thi + (size_t)l * WSZ, w2tlo + (size_t)l * WSZ);
    }
    wprep_kernel<<<(HDIM * HDIM + 255) / 256, 256, 0, stream>>>(Wf1, HDIM, HDIM, wf1thi, wf1tlo);
    wprep_kernel<<<(HDIM * EDIM + 255) / 256, 256, 0, stream>>>(Wf2, HDIM, EDIM, wf2thi, wf2tlo);

    // 4. GIN layers
    for (int l = 0; l < NLAYERS; ++l) {
        gather_kernel<<<N_NODES / 4, 256, 0, stream>>>(h, row_ptr, eids, zin_hi, zin_lo);
        for (long r0 = 0; r0 < N_NODES; r0 += chunk) {
            const int mc = (int)((N_NODES - r0 < chunk) ? (N_NODES - r0) : chunk);
            // z2 = relu(zin @ W1[l] + b1[l])  [mc, 512] -> bf16 pair
            gemm_mfma<2><<<dim3(2 * HDIM / 128, (mc + 127) / 128), 256, 0, stream>>>(
                zin_hi + (size_t)r0 * HDIM, zin_lo + (size_t)r0 * HDIM,
                w1thi + (size_t)l * WSZ, w1tlo + (size_t)l * WSZ,
                b1 + (size_t)l * 2 * HDIM, nullptr, z2hi, z2lo, mc, 2 * HDIM, HDIM);
            // h = relu(z2 @ W2[l] + b2[l])    [mc, 256] -> fp32
            gemm_mfma<1><<<dim3(HDIM / 128, (mc + 127) / 128), 256, 0, stream>>>(
                z2hi, z2lo, w2thi + (size_t)l * WSZ, w2tlo + (size_t)l * WSZ,
                b2 + (size_t)l * HDIM, h + (size_t)r0 * HDIM, nullptr, nullptr, mc, HDIM, 2 * HDIM);
        }
    }

    // 5. pool (split-write)
    pool_kernel<<<N_GRAPHS, HDIM, 0, stream>>>(h, batch, hg_hi, hg_lo);

    // 6. head
    gemm_mfma<2><<<dim3(HDIM / 128, (N_GRAPHS + 127) / 128), 256, 0, stream>>>(
        hg_hi, hg_lo, wf1thi, wf1tlo, bf1, nullptr, hg1_hi, hg1_lo, N_GRAPHS, HDIM, HDIM);
    gemm_mfma<0><<<dim3(EDIM / 128, (N_GRAPHS + 127) / 128), 256, 0, stream>>>(
        hg1_hi, hg1_lo, wf2thi, wf2tlo, bf2, out, nullptr, nullptr, N_GRAPHS, EDIM, HDIM);
}

// Round 5
// 1814.129 us; speedup vs baseline: 3.4759x; 1.0765x over previous
//
#include <hip/hip_runtime.h>

#define N_NODES 100000
#define N_EDGES 200000
#define N_GRAPHS 4000
#define F_IN 44
#define HDIM 256
#define EDIM 512
#define NLAYERS 4

typedef float floatx4 __attribute__((ext_vector_type(4)));
typedef short bhalf8 __attribute__((ext_vector_type(8)));
typedef unsigned short ushort_t;

__device__ __forceinline__ unsigned short f2bf(float f) {
    unsigned int u = __float_as_uint(f);
    u += 0x7FFFu + ((u >> 16) & 1u);          // RNE
    return (unsigned short)(u >> 16);
}
__device__ __forceinline__ float bf2f(unsigned short s) {
    return __uint_as_float(((unsigned int)s) << 16);
}

// async global->LDS, 16B per lane. ldst must be wave-uniform; gsrc per-lane.
__device__ __forceinline__ void gload16(const void* gsrc, void* ldst) {
    __builtin_amdgcn_global_load_lds(
        (const __attribute__((address_space(1))) void*)gsrc,
        (__attribute__((address_space(3))) void*)ldst, 16, 0, 0);
}

// ---------------- zero fill ----------------
__global__ void zero_kernel(float* __restrict__ p, size_t n4) {
    size_t i = (size_t)blockIdx.x * blockDim.x + threadIdx.x;
    const size_t stride = (size_t)gridDim.x * blockDim.x;
    const float4 z = make_float4(0.f, 0.f, 0.f, 0.f);
    for (; i < n4; i += stride) ((float4*)p)[i] = z;
}

// ---------------- atom MLP: h = relu(x @ W_atom + b_atom), 8 nodes/block ----------------
__global__ __launch_bounds__(256) void atom_kernel(const float* __restrict__ x,
                                                   const float* __restrict__ W,
                                                   const float* __restrict__ b,
                                                   float* __restrict__ h) {
    __shared__ float xs[8][F_IN];
    const int n0 = blockIdx.x * 8;
    const int t = threadIdx.x;
    for (int i = t; i < 8 * F_IN; i += 256) {
        const int n = i / F_IN, k = i % F_IN;
        xs[n][k] = x[(size_t)(n0 + n) * F_IN + k];
    }
    __syncthreads();
    const int j = t;
    float acc[8];
    const float bj = b[j];
#pragma unroll
    for (int n = 0; n < 8; ++n) acc[n] = bj;
    for (int k = 0; k < F_IN; ++k) {
        const float w = W[k * HDIM + j];
#pragma unroll
        for (int n = 0; n < 8; ++n) acc[n] = fmaf(xs[n][k], w, acc[n]);
    }
#pragma unroll
    for (int n = 0; n < 8; ++n) h[(size_t)(n0 + n) * HDIM + j] = fmaxf(acc[n], 0.f);
}

// ---------------- CSR build ----------------
__global__ void hist_kernel(const int* __restrict__ dst, int* __restrict__ deg) {
    const int e = blockIdx.x * 256 + threadIdx.x;
    if (e < N_EDGES) atomicAdd(&deg[dst[e]], 1);
}

__global__ void scan1_kernel(const int* __restrict__ deg, int* __restrict__ row_ptr,
                             int* __restrict__ blk) {
    __shared__ int s[256];
    const int i = blockIdx.x * 256 + threadIdx.x;
    s[threadIdx.x] = (i < N_NODES) ? deg[i] : 0;
    __syncthreads();
    for (int off = 1; off < 256; off <<= 1) {
        int t = (threadIdx.x >= off) ? s[threadIdx.x - off] : 0;
        __syncthreads();
        s[threadIdx.x] += t;
        __syncthreads();
    }
    if (i < N_NODES) row_ptr[i + 1] = s[threadIdx.x];
    if (threadIdx.x == 255) blk[blockIdx.x] = s[255];
}

__global__ void scan2_kernel(int* __restrict__ blk, int nb) {
    if (threadIdx.x == 0 && blockIdx.x == 0) {
        int run = 0;
        for (int b = 0; b < nb; ++b) { const int t = blk[b]; blk[b] = run; run += t; }
    }
}

__global__ void scan3_kernel(int* __restrict__ row_ptr, const int* __restrict__ blk) {
    const int i = blockIdx.x * 256 + threadIdx.x;
    if (i < N_NODES) row_ptr[i + 1] += blk[i >> 8];
    if (i == 0) row_ptr[0] = 0;
}

__global__ void cursor_kernel(const int* __restrict__ row_ptr, int* __restrict__ cursor) {
    const int i = blockIdx.x * 256 + threadIdx.x;
    if (i < N_NODES) cursor[i] = row_ptr[i];
}

__global__ void fill_kernel(const int* __restrict__ src, const int* __restrict__ dst,
                            int* __restrict__ cursor, int* __restrict__ eids) {
    const int e = blockIdx.x * 256 + threadIdx.x;
    if (e < N_EDGES) {
        const int pos = atomicAdd(&cursor[dst[e]], 1);
        eids[pos] = src[e];
    }
}

// ------- gather: z = h + sum_neigh h; write hi|lo K-concat bf16 [n][2*HDIM] -------
__global__ void gather_kernel(const float* __restrict__ h, const int* __restrict__ row_ptr,
                              const int* __restrict__ eids, unsigned short* __restrict__ z) {
    const int tid = threadIdx.x;
    const int n = blockIdx.x * 4 + (tid >> 6);
    const int t = tid & 63;
    const float4* h4 = (const float4*)h;
    float4 acc = h4[(size_t)n * 64 + t];
    const int s = row_ptr[n], e = row_ptr[n + 1];
    for (int i = s; i < e; ++i) {
        const float4 v = h4[(size_t)eids[i] * 64 + t];
        acc.x += v.x; acc.y += v.y; acc.z += v.z; acc.w += v.w;
    }
    ushort4 hi, lo;
    hi.x = f2bf(acc.x); lo.x = f2bf(acc.x - bf2f(hi.x));
    hi.y = f2bf(acc.y); lo.y = f2bf(acc.y - bf2f(hi.y));
    hi.z = f2bf(acc.z); lo.z = f2bf(acc.z - bf2f(hi.z));
    hi.w = f2bf(acc.w); lo.w = f2bf(acc.w - bf2f(hi.w));
    unsigned short* zr = z + (size_t)n * (2 * HDIM);
    *(ushort4*)(zr + t * 4) = hi;
    *(ushort4*)(zr + HDIM + t * 4) = lo;
}

// ------- weight prep: W[K][N] fp32 -> T[N][2K] bf16 (hi cols 0..K-1, lo cols K..2K-1) ---
__global__ void wprep_kernel(const float* __restrict__ W, int K, int N,
                             unsigned short* __restrict__ T) {
    const int idx = blockIdx.x * 256 + threadIdx.x;
    if (idx < K * N) {
        const int k = idx / N, n = idx % N;
        const float v = W[idx];
        const unsigned short hh = f2bf(v);
        T[(size_t)n * 2 * K + k] = hh;
        T[(size_t)n * 2 * K + K + k] = f2bf(v - bf2f(hh));
    }
}

// ---------------- MFMA GEMM: C = act(A @ B + bias) on K-concat bf16 ----------------
// A [M][KK] bf16 row-major, BT [N][KK] bf16. KK = 2*K_logical, multiple of 32.
// 128x128 tile, BK=32, 256 thr = 4 waves (2x2 of 64x64), 16x16x32 MFMA.
// Staging: global_load_lds width 16, linear LDS [128][32] ushort (conflict-free).
// OUT: 0 = fp32, 1 = fp32+relu, 2 = bf16 hi|lo K-concat (stride 2N) + relu
template <int OUT>
__global__ __launch_bounds__(256)
void gemm_mfma(const unsigned short* __restrict__ A, const unsigned short* __restrict__ BT,
               const float* __restrict__ bias, float* __restrict__ C,
               unsigned short* __restrict__ Z, int M, int N, int KK) {
    __shared__ __align__(16) unsigned short As[128][32];   // 8 KB
    __shared__ __align__(16) unsigned short Bs[128][32];   // 8 KB

    const int tid = threadIdx.x;
    const int lane = tid & 63;
    const int w = tid >> 6;
    const int row0 = blockIdx.y * 128;
    const int col0 = blockIdx.x * 128;

    // staging: wave w stages tile rows [w*32, w*32+32), 2 instrs x 16 rows each
    const int lrow = lane >> 2;            // 0..15 row within 16-row group
    const int scol = (lane & 3) * 8;       // ushort col (16B granule)

    // fragment coords
    const int wr = w >> 1, wc = w & 1;
    const int lr = lane & 15;
    const int kb = (lane >> 4) * 8;

    floatx4 acc[4][4];
#pragma unroll
    for (int m = 0; m < 4; ++m)
#pragma unroll
        for (int n = 0; n < 4; ++n) acc[m][n] = (floatx4){0.f, 0.f, 0.f, 0.f};

    const int NT = KK >> 5;
    for (int t = 0; t < NT; ++t) {
        const int k0 = t << 5;
#pragma unroll
        for (int j = 0; j < 2; ++j) {
            const int trow = w * 32 + j * 16;              // wave-uniform
            const int ga = row0 + trow + lrow;             // per-lane global row
            if (ga < M)
                gload16(A + (size_t)ga * KK + k0 + scol, &As[trow][0]);
            gload16(BT + (size_t)(col0 + trow + lrow) * KK + k0 + scol, &Bs[trow][0]);
        }
        __syncthreads();   // drains vmcnt, then barrier

        bhalf8 fa[4], fb[4];
#pragma unroll
        for (int m = 0; m < 4; ++m) fa[m] = *(const bhalf8*)&As[wr * 64 + m * 16 + lr][kb];
#pragma unroll
        for (int n = 0; n < 4; ++n) fb[n] = *(const bhalf8*)&Bs[wc * 64 + n * 16 + lr][kb];
#pragma unroll
        for (int m = 0; m < 4; ++m)
#pragma unroll
            for (int n = 0; n < 4; ++n)
                acc[m][n] = __builtin_amdgcn_mfma_f32_16x16x32_bf16(fa[m], fb[n], acc[m][n], 0, 0, 0);
        __syncthreads();   // protect LDS before next stage
    }

    // epilogue: C/D layout col = lane&15, row = (lane>>4)*4 + j
    const int rgrp = (lane >> 4) * 4;
#pragma unroll
    for (int n = 0; n < 4; ++n) {
        const int col = col0 + wc * 64 + n * 16 + lr;
        const float bv = bias[col];
#pragma unroll
        for (int m = 0; m < 4; ++m) {
            const int rw = row0 + wr * 64 + m * 16 + rgrp;
#pragma unroll
            for (int j = 0; j < 4; ++j) {
                const int row = rw + j;
                if (row < M) {
                    float v = acc[m][n][j] + bv;
                    if (OUT >= 1) v = fmaxf(v, 0.f);
                    if (OUT == 2) {
                        const unsigned short hh = f2bf(v);
                        unsigned short* zr = Z + (size_t)row * 2 * N;
                        zr[col] = hh;
                        zr[N + col] = f2bf(v - bf2f(hh));
                    } else {
                        C[(size_t)row * N + col] = v;
                    }
                }
            }
        }
    }
}

// ------- pool: sorted-batch segment mean -> hi|lo K-concat [g][2*HDIM] -------
__global__ void pool_kernel(const float* __restrict__ h, const int* __restrict__ batch,
                            unsigned short* __restrict__ gz) {
    __shared__ int sse[2];
    const int g = blockIdx.x;
    if (threadIdx.x < 2) {
        const int target = g + threadIdx.x;
        int lo = 0, hi = N_NODES;
        while (lo < hi) {
            const int mid = (lo + hi) >> 1;
            if (batch[mid] < target) lo = mid + 1; else hi = mid;
        }
        sse[threadIdx.x] = lo;
    }
    __syncthreads();
    const int s = sse[0], e = sse[1];
    const int j = threadIdx.x;
    float acc = 0.f;
    for (int n = s; n < e; ++n) acc += h[(size_t)n * HDIM + j];
    const float v = acc * ((e > s) ? 1.f / (float)(e - s) : 1.f);
    const unsigned short hh = f2bf(v);
    gz[(size_t)g * 2 * HDIM + j] = hh;
    gz[(size_t)g * 2 * HDIM + HDIM + j] = f2bf(v - bf2f(hh));
}

extern "C" void kernel_launch(void* const* d_in, const int* in_sizes, int n_in,
                              void* d_out, int out_size, void* d_ws, size_t ws_size,
                              hipStream_t stream) {
    const float* x      = (const float*)d_in[0];
    const int*   eidx   = (const int*)d_in[1];
    const int*   batch  = (const int*)d_in[2];
    const float* W_atom = (const float*)d_in[3];
    const float* b_atom = (const float*)d_in[4];
    const float* W1     = (const float*)d_in[5];
    const float* b1     = (const float*)d_in[6];
    const float* W2     = (const float*)d_in[7];
    const float* b2     = (const float*)d_in[8];
    const float* Wf1    = (const float*)d_in[9];
    const float* bf1    = (const float*)d_in[10];
    const float* Wf2    = (const float*)d_in[11];
    const float* bf2    = (const float*)d_in[12];
    float* out = (float*)d_out;

    const int* src = eidx;
    const int* dst = eidx + N_EDGES;

    const size_t NH = (size_t)N_NODES * HDIM;           // 25.6M elems
    const int WSZ = HDIM * 2 * HDIM;                    // fp32 elems per layer weight

    // ---- workspace layout ----
    char* base = (char*)d_ws;
    size_t off = 0;
    float* h = (float*)(base + off);                        off += NH * 4;
    unsigned short* zin = (unsigned short*)(base + off);    off += NH * 2 * 2;  // [N][512]
    int* deg     = (int*)(base + off);            off += (size_t)N_NODES * 4;
    int* row_ptr = (int*)(base + off);            off += (size_t)(N_NODES + 1) * 4;
    int* cursor  = (int*)(base + off);            off += (size_t)N_NODES * 4;
    int* eids    = (int*)(base + off);            off += (size_t)N_EDGES * 4;
    int* blk     = (int*)(base + off);            off += 512 * 4;
    off = (off + 255) & ~(size_t)255;
    // transposed K-concat weights: T1 [512][512], T2 [256][1024] per layer
    unsigned short* t1 = (unsigned short*)(base + off); off += (size_t)NLAYERS * WSZ * 2 * 2;
    unsigned short* t2 = (unsigned short*)(base + off); off += (size_t)NLAYERS * WSZ * 2 * 2;
    unsigned short* tf1 = (unsigned short*)(base + off); off += (size_t)HDIM * HDIM * 2 * 2;
    unsigned short* tf2 = (unsigned short*)(base + off); off += (size_t)HDIM * EDIM * 2 * 2;
    off = (off + 255) & ~(size_t)255;

    const size_t avail = (ws_size > off) ? ws_size - off : 0;
    long chunk = (long)(avail / ((size_t)EDIM * 2 * 2));   // z2 row = 2*EDIM ushorts
    if (chunk >= N_NODES) chunk = N_NODES;
    else chunk &= ~127L;
    if (chunk < 128) chunk = 128;
    unsigned short* z2 = (unsigned short*)(base + off);    // [chunk][1024]

    // head buffers overlap the (dead-after-layers) zin region
    const size_t GH2 = (size_t)N_GRAPHS * 2 * HDIM;
    unsigned short* hg  = zin;            // [4000][512]
    unsigned short* hg1 = zin + GH2;      // [4000][512]

    const int nb = (N_NODES + 255) / 256;
    const int T1SZ = 2 * WSZ;                              // ushorts per layer (T1)
    const int T2SZ = 2 * WSZ;

    // 1. atom MLP
    atom_kernel<<<N_NODES / 8, 256, 0, stream>>>(x, W_atom, b_atom, h);

    // 2. CSR build
    zero_kernel<<<128, 256, 0, stream>>>((float*)deg, N_NODES / 4);
    hist_kernel<<<(N_EDGES + 255) / 256, 256, 0, stream>>>(dst, deg);
    scan1_kernel<<<nb, 256, 0, stream>>>(deg, row_ptr, blk);
    scan2_kernel<<<1, 64, 0, stream>>>(blk, nb);
    scan3_kernel<<<nb, 256, 0, stream>>>(row_ptr, blk);
    cursor_kernel<<<nb, 256, 0, stream>>>(row_ptr, cursor);
    fill_kernel<<<(N_EDGES + 255) / 256, 256, 0, stream>>>(src, dst, cursor, eids);

    // 3. weight transpose + K-concat bf16 split
    for (int l = 0; l < NLAYERS; ++l) {
        wprep_kernel<<<(WSZ + 255) / 256, 256, 0, stream>>>(
            W1 + (size_t)l * WSZ, HDIM, 2 * HDIM, t1 + (size_t)l * T1SZ);
        wprep_kernel<<<(WSZ + 255) / 256, 256, 0, stream>>>(
            W2 + (size_t)l * WSZ, 2 * HDIM, HDIM, t2 + (size_t)l * T2SZ);
    }
    wprep_kernel<<<(HDIM * HDIM + 255) / 256, 256, 0, stream>>>(Wf1, HDIM, HDIM, tf1);
    wprep_kernel<<<(HDIM * EDIM + 255) / 256, 256, 0, stream>>>(Wf2, HDIM, EDIM, tf2);

    // 4. GIN layers
    for (int l = 0; l < NLAYERS; ++l) {
        gather_kernel<<<N_NODES / 4, 256, 0, stream>>>(h, row_ptr, eids, zin);
        for (long r0 = 0; r0 < N_NODES; r0 += chunk) {
            const int mc = (int)((N_NODES - r0 < chunk) ? (N_NODES - r0) : chunk);
            // z2 = relu(zin @ W1[l] + b1[l])  [mc, 512] -> K-concat bf16 [mc][1024]
            gemm_mfma<2><<<dim3(2 * HDIM / 128, (mc + 127) / 128), 256, 0, stream>>>(
                zin + (size_t)r0 * 2 * HDIM, t1 + (size_t)l * T1SZ,
                b1 + (size_t)l * 2 * HDIM, nullptr, z2, mc, 2 * HDIM, 2 * HDIM);
            // h = relu(z2 @ W2[l] + b2[l])    [mc, 256] -> fp32
            gemm_mfma<1><<<dim3(HDIM / 128, (mc + 127) / 128), 256, 0, stream>>>(
                z2, t2 + (size_t)l * T2SZ,
                b2 + (size_t)l * HDIM, h + (size_t)r0 * HDIM, nullptr, mc, HDIM, 4 * HDIM);
        }
    }

    // 5. pool (K-concat split write)
    pool_kernel<<<N_GRAPHS, HDIM, 0, stream>>>(h, batch, hg);

    // 6. head
    gemm_mfma<2><<<dim3(HDIM / 128, (N_GRAPHS + 127) / 128), 256, 0, stream>>>(
        hg, tf1, bf1, nullptr, hg1, N_GRAPHS, HDIM, 2 * HDIM);
    gemm_mfma<0><<<dim3(EDIM / 128, (N_GRAPHS + 127) / 128), 256, 0, stream>>>(
        hg1, tf2, bf2, out, nullptr, N_GRAPHS, EDIM, 2 * HDIM);
}

// Round 6
// 1680.814 us; speedup vs baseline: 3.7516x; 1.0793x over previous
//
#include <hip/hip_runtime.h>

#define N_NODES 100000
#define N_EDGES 200000
#define N_GRAPHS 4000
#define F_IN 44
#define HDIM 256
#define EDIM 512
#define NLAYERS 4

typedef float floatx4 __attribute__((ext_vector_type(4)));
typedef short bhalf8 __attribute__((ext_vector_type(8)));

__device__ __forceinline__ unsigned short f2bf(float f) {
    unsigned int u = __float_as_uint(f);
    u += 0x7FFFu + ((u >> 16) & 1u);          // RNE
    return (unsigned short)(u >> 16);
}
__device__ __forceinline__ float bf2f(unsigned short s) {
    return __uint_as_float(((unsigned int)s) << 16);
}

// async global->LDS, 16B per lane. ldst wave-uniform base; gsrc per-lane.
__device__ __forceinline__ void gload16(const void* gsrc, void* ldst) {
    __builtin_amdgcn_global_load_lds(
        (const __attribute__((address_space(1))) void*)gsrc,
        (__attribute__((address_space(3))) void*)ldst, 16, 0, 0);
}

// ---------------- zero fill ----------------
__global__ void zero_kernel(float* __restrict__ p, size_t n4) {
    size_t i = (size_t)blockIdx.x * blockDim.x + threadIdx.x;
    const size_t stride = (size_t)gridDim.x * blockDim.x;
    const float4 z = make_float4(0.f, 0.f, 0.f, 0.f);
    for (; i < n4; i += stride) ((float4*)p)[i] = z;
}

// ---------------- atom MLP: h = relu(x @ W_atom + b_atom), 8 nodes/block ----------------
__global__ __launch_bounds__(256) void atom_kernel(const float* __restrict__ x,
                                                   const float* __restrict__ W,
                                                   const float* __restrict__ b,
                                                   float* __restrict__ h) {
    __shared__ float xs[8][F_IN];
    const int n0 = blockIdx.x * 8;
    const int t = threadIdx.x;
    for (int i = t; i < 8 * F_IN; i += 256) {
        const int n = i / F_IN, k = i % F_IN;
        xs[n][k] = x[(size_t)(n0 + n) * F_IN + k];
    }
    __syncthreads();
    const int j = t;
    float acc[8];
    const float bj = b[j];
#pragma unroll
    for (int n = 0; n < 8; ++n) acc[n] = bj;
    for (int k = 0; k < F_IN; ++k) {
        const float w = W[k * HDIM + j];
#pragma unroll
        for (int n = 0; n < 8; ++n) acc[n] = fmaf(xs[n][k], w, acc[n]);
    }
#pragma unroll
    for (int n = 0; n < 8; ++n) h[(size_t)(n0 + n) * HDIM + j] = fmaxf(acc[n], 0.f);
}

// ---------------- CSR build ----------------
__global__ void hist_kernel(const int* __restrict__ dst, int* __restrict__ deg) {
    const int e = blockIdx.x * 256 + threadIdx.x;
    if (e < N_EDGES) atomicAdd(&deg[dst[e]], 1);
}

__global__ void scan1_kernel(const int* __restrict__ deg, int* __restrict__ row_ptr,
                             int* __restrict__ blk) {
    __shared__ int s[256];
    const int i = blockIdx.x * 256 + threadIdx.x;
    s[threadIdx.x] = (i < N_NODES) ? deg[i] : 0;
    __syncthreads();
    for (int off = 1; off < 256; off <<= 1) {
        int t = (threadIdx.x >= off) ? s[threadIdx.x - off] : 0;
        __syncthreads();
        s[threadIdx.x] += t;
        __syncthreads();
    }
    if (i < N_NODES) row_ptr[i + 1] = s[threadIdx.x];
    if (threadIdx.x == 255) blk[blockIdx.x] = s[255];
}

__global__ void scan2_kernel(int* __restrict__ blk, int nb) {
    if (threadIdx.x == 0 && blockIdx.x == 0) {
        int run = 0;
        for (int b = 0; b < nb; ++b) { const int t = blk[b]; blk[b] = run; run += t; }
    }
}

__global__ void scan3_kernel(int* __restrict__ row_ptr, const int* __restrict__ blk) {
    const int i = blockIdx.x * 256 + threadIdx.x;
    if (i < N_NODES) row_ptr[i + 1] += blk[i >> 8];
    if (i == 0) row_ptr[0] = 0;
}

__global__ void cursor_kernel(const int* __restrict__ row_ptr, int* __restrict__ cursor) {
    const int i = blockIdx.x * 256 + threadIdx.x;
    if (i < N_NODES) cursor[i] = row_ptr[i];
}

__global__ void fill_kernel(const int* __restrict__ src, const int* __restrict__ dst,
                            int* __restrict__ cursor, int* __restrict__ eids) {
    const int e = blockIdx.x * 256 + threadIdx.x;
    if (e < N_EDGES) {
        const int pos = atomicAdd(&cursor[dst[e]], 1);
        eids[pos] = src[e];
    }
}

// ------- gather: z = h + sum_neigh h; write hi|lo K-concat bf16 [n][2*HDIM] -------
__global__ void gather_kernel(const float* __restrict__ h, const int* __restrict__ row_ptr,
                              const int* __restrict__ eids, unsigned short* __restrict__ z) {
    const int tid = threadIdx.x;
    const int n = blockIdx.x * 4 + (tid >> 6);
    const int t = tid & 63;
    const float4* h4 = (const float4*)h;
    float4 acc = h4[(size_t)n * 64 + t];
    const int s = row_ptr[n], e = row_ptr[n + 1];
    for (int i = s; i < e; ++i) {
        const float4 v = h4[(size_t)eids[i] * 64 + t];
        acc.x += v.x; acc.y += v.y; acc.z += v.z; acc.w += v.w;
    }
    ushort4 hi, lo;
    hi.x = f2bf(acc.x); lo.x = f2bf(acc.x - bf2f(hi.x));
    hi.y = f2bf(acc.y); lo.y = f2bf(acc.y - bf2f(hi.y));
    hi.z = f2bf(acc.z); lo.z = f2bf(acc.z - bf2f(hi.z));
    hi.w = f2bf(acc.w); lo.w = f2bf(acc.w - bf2f(hi.w));
    unsigned short* zr = z + (size_t)n * (2 * HDIM);
    *(ushort4*)(zr + t * 4) = hi;
    *(ushort4*)(zr + HDIM + t * 4) = lo;
}

// ------- weight prep: W[K][N] fp32 -> T[N][2K] bf16 (hi cols 0..K-1, lo cols K..2K-1) ---
__global__ void wprep_kernel(const float* __restrict__ W, int K, int N,
                             unsigned short* __restrict__ T) {
    const int idx = blockIdx.x * 256 + threadIdx.x;
    if (idx < K * N) {
        const int k = idx / N, n = idx % N;
        const float v = W[idx];
        const unsigned short hh = f2bf(v);
        T[(size_t)n * 2 * K + k] = hh;
        T[(size_t)n * 2 * K + K + k] = f2bf(v - bf2f(hh));
    }
}

// ---------------- MFMA GEMM: C = act(A @ B + bias) on K-concat bf16 ----------------
// A [M][KK] bf16 row-major, BT [N][KK] bf16. KK multiple of 64.
// 128x128 tile, BK=64, 256 thr = 4 waves (2x2 of 64x64), 16x16x32 MFMA x2 k-steps.
// LDS: [128 rows][8 granules of 16B], granule XOR-swizzled: phys = logical ^ (row&7).
// Staged via global_load_lds w16 with pre-swizzled per-lane global source (T2+m173).
// 1D grid with XCD-bijective remap (T1/m204), row-major within col-panel.
// OUT: 0 = fp32, 1 = fp32+relu, 2 = bf16 hi|lo K-concat (stride 2N) + relu
template <int OUT>
__global__ __launch_bounds__(256)
void gemm_mfma(const unsigned short* __restrict__ A, const unsigned short* __restrict__ BT,
               const float* __restrict__ bias, float* __restrict__ C,
               unsigned short* __restrict__ Z, int M, int N, int KK) {
    __shared__ __align__(16) unsigned short As[128 * 64];   // 16 KB
    __shared__ __align__(16) unsigned short Bs[128 * 64];   // 16 KB

    const int nrow = (M + 127) >> 7;
    const int G = gridDim.x;
    int wg = blockIdx.x;
    {   // bijective XCD remap (m204)
        const int q = G >> 3, r = G & 7;
        const int xx = wg & 7, o = wg >> 3;
        wg = (xx < r ? xx * (q + 1) : r * (q + 1) + (xx - r) * q) + o;
    }
    const int row0 = (wg % nrow) << 7;
    const int col0 = (wg / nrow) << 7;

    const int tid = threadIdx.x;
    const int lane = tid & 63;
    const int w = tid >> 6;

    // staging: lane covers row (R + lane>>3), physical granule (lane&7);
    // source logical granule = (lane&7) ^ ((lane>>3)&7)   [R % 8 == 0]
    const int lrow8 = lane >> 3;                       // 0..7
    const int sgran = ((lane & 7) ^ (lrow8 & 7)) << 3; // ushort offset within row

    const int wr = w >> 1, wc = w & 1;
    const int lr = lane & 15;
    const int l4 = lane >> 4;                          // 0..3

    floatx4 acc[4][4];
#pragma unroll
    for (int m = 0; m < 4; ++m)
#pragma unroll
        for (int n = 0; n < 4; ++n) acc[m][n] = (floatx4){0.f, 0.f, 0.f, 0.f};

    const int NT = KK >> 6;
    for (int t = 0; t < NT; ++t) {
        const int k0 = t << 6;
#pragma unroll
        for (int j = 0; j < 4; ++j) {
            const int R = (w << 5) + (j << 3);         // wave-uniform row base (%8==0)
            const int ar = row0 + R + lrow8;
            if (ar < M) gload16(A + (size_t)ar * KK + k0 + sgran, &As[R << 6]);
            gload16(BT + (size_t)(col0 + R + lrow8) * KK + k0 + sgran, &Bs[R << 6]);
        }
        __syncthreads();
#pragma unroll
        for (int s = 0; s < 2; ++s) {
            const int pg = ((((s << 2) + l4) ^ (lr & 7)) << 3); // swizzled granule (ushorts)
            bhalf8 fa[4], fb[4];
#pragma unroll
            for (int m = 0; m < 4; ++m)
                fa[m] = *(const bhalf8*)&As[(((wr << 6) + (m << 4) + lr) << 6) + pg];
#pragma unroll
            for (int n = 0; n < 4; ++n)
                fb[n] = *(const bhalf8*)&Bs[(((wc << 6) + (n << 4) + lr) << 6) + pg];
#pragma unroll
            for (int m = 0; m < 4; ++m)
#pragma unroll
                for (int n = 0; n < 4; ++n)
                    acc[m][n] = __builtin_amdgcn_mfma_f32_16x16x32_bf16(fa[m], fb[n], acc[m][n], 0, 0, 0);
        }
        __syncthreads();
    }

    // epilogue: C/D layout col = lane&15, row = (lane>>4)*4 + j
    const int rgrp = l4 * 4;
#pragma unroll
    for (int n = 0; n < 4; ++n) {
        const int col = col0 + wc * 64 + n * 16 + lr;
        const float bv = bias[col];
#pragma unroll
        for (int m = 0; m < 4; ++m) {
            const int rw = row0 + wr * 64 + m * 16 + rgrp;
#pragma unroll
            for (int j = 0; j < 4; ++j) {
                const int row = rw + j;
                if (row < M) {
                    float v = acc[m][n][j] + bv;
                    if (OUT >= 1) v = fmaxf(v, 0.f);
                    if (OUT == 2) {
                        const unsigned short hh = f2bf(v);
                        unsigned short* zr = Z + (size_t)row * 2 * N;
                        zr[col] = hh;
                        zr[N + col] = f2bf(v - bf2f(hh));
                    } else {
                        C[(size_t)row * N + col] = v;
                    }
                }
            }
        }
    }
}

// ------- pool: sorted-batch segment mean -> hi|lo K-concat [g][2*HDIM] -------
__global__ void pool_kernel(const float* __restrict__ h, const int* __restrict__ batch,
                            unsigned short* __restrict__ gz) {
    __shared__ int sse[2];
    const int g = blockIdx.x;
    if (threadIdx.x < 2) {
        const int target = g + threadIdx.x;
        int lo = 0, hi = N_NODES;
        while (lo < hi) {
            const int mid = (lo + hi) >> 1;
            if (batch[mid] < target) lo = mid + 1; else hi = mid;
        }
        sse[threadIdx.x] = lo;
    }
    __syncthreads();
    const int s = sse[0], e = sse[1];
    const int j = threadIdx.x;
    float acc = 0.f;
    for (int n = s; n < e; ++n) acc += h[(size_t)n * HDIM + j];
    const float v = acc * ((e > s) ? 1.f / (float)(e - s) : 1.f);
    const unsigned short hh = f2bf(v);
    gz[(size_t)g * 2 * HDIM + j] = hh;
    gz[(size_t)g * 2 * HDIM + HDIM + j] = f2bf(v - bf2f(hh));
}

extern "C" void kernel_launch(void* const* d_in, const int* in_sizes, int n_in,
                              void* d_out, int out_size, void* d_ws, size_t ws_size,
                              hipStream_t stream) {
    const float* x      = (const float*)d_in[0];
    const int*   eidx   = (const int*)d_in[1];
    const int*   batch  = (const int*)d_in[2];
    const float* W_atom = (const float*)d_in[3];
    const float* b_atom = (const float*)d_in[4];
    const float* W1     = (const float*)d_in[5];
    const float* b1     = (const float*)d_in[6];
    const float* W2     = (const float*)d_in[7];
    const float* b2     = (const float*)d_in[8];
    const float* Wf1    = (const float*)d_in[9];
    const float* bf1    = (const float*)d_in[10];
    const float* Wf2    = (const float*)d_in[11];
    const float* bf2    = (const float*)d_in[12];
    float* out = (float*)d_out;

    const int* src = eidx;
    const int* dst = eidx + N_EDGES;

    const size_t NH = (size_t)N_NODES * HDIM;           // 25.6M elems
    const int WSZ = HDIM * 2 * HDIM;                    // fp32 elems per layer weight

    // ---- workspace layout ----
    char* base = (char*)d_ws;
    size_t off = 0;
    float* h = (float*)(base + off);                        off += NH * 4;
    unsigned short* zin = (unsigned short*)(base + off);    off += NH * 2 * 2;  // [N][512]
    int* deg     = (int*)(base + off);            off += (size_t)N_NODES * 4;
    int* row_ptr = (int*)(base + off);            off += (size_t)(N_NODES + 1) * 4;
    int* cursor  = (int*)(base + off);            off += (size_t)N_NODES * 4;
    int* eids    = (int*)(base + off);            off += (size_t)N_EDGES * 4;
    int* blk     = (int*)(base + off);            off += 512 * 4;
    off = (off + 255) & ~(size_t)255;
    // transposed K-concat weights: T1 [512][512], T2 [256][1024] per layer
    unsigned short* t1 = (unsigned short*)(base + off); off += (size_t)NLAYERS * WSZ * 2 * 2;
    unsigned short* t2 = (unsigned short*)(base + off); off += (size_t)NLAYERS * WSZ * 2 * 2;
    unsigned short* tf1 = (unsigned short*)(base + off); off += (size_t)HDIM * HDIM * 2 * 2;
    unsigned short* tf2 = (unsigned short*)(base + off); off += (size_t)HDIM * EDIM * 2 * 2;
    off = (off + 255) & ~(size_t)255;

    const size_t avail = (ws_size > off) ? ws_size - off : 0;
    long chunk = (long)(avail / ((size_t)EDIM * 2 * 2));   // z2 row = 2*EDIM ushorts
    if (chunk > 32768) chunk = 32768;                      // keep z2 (64MB) L3-resident
    if (chunk >= N_NODES) chunk = N_NODES;
    else chunk &= ~127L;
    if (chunk < 128) chunk = 128;
    unsigned short* z2 = (unsigned short*)(base + off);    // [chunk][1024]

    // head buffers overlap the (dead-after-layers) zin region
    const size_t GH2 = (size_t)N_GRAPHS * 2 * HDIM;
    unsigned short* hg  = zin;            // [4000][512]
    unsigned short* hg1 = zin + GH2;      // [4000][512]

    const int nb = (N_NODES + 255) / 256;
    const int T1SZ = 2 * WSZ;
    const int T2SZ = 2 * WSZ;

    // 1. atom MLP
    atom_kernel<<<N_NODES / 8, 256, 0, stream>>>(x, W_atom, b_atom, h);

    // 2. CSR build
    zero_kernel<<<128, 256, 0, stream>>>((float*)deg, N_NODES / 4);
    hist_kernel<<<(N_EDGES + 255) / 256, 256, 0, stream>>>(dst, deg);
    scan1_kernel<<<nb, 256, 0, stream>>>(deg, row_ptr, blk);
    scan2_kernel<<<1, 64, 0, stream>>>(blk, nb);
    scan3_kernel<<<nb, 256, 0, stream>>>(row_ptr, blk);
    cursor_kernel<<<nb, 256, 0, stream>>>(row_ptr, cursor);
    fill_kernel<<<(N_EDGES + 255) / 256, 256, 0, stream>>>(src, dst, cursor, eids);

    // 3. weight transpose + K-concat bf16 split
    for (int l = 0; l < NLAYERS; ++l) {
        wprep_kernel<<<(WSZ + 255) / 256, 256, 0, stream>>>(
            W1 + (size_t)l * WSZ, HDIM, 2 * HDIM, t1 + (size_t)l * T1SZ);
        wprep_kernel<<<(WSZ + 255) / 256, 256, 0, stream>>>(
            W2 + (size_t)l * WSZ, 2 * HDIM, HDIM, t2 + (size_t)l * T2SZ);
    }
    wprep_kernel<<<(HDIM * HDIM + 255) / 256, 256, 0, stream>>>(Wf1, HDIM, HDIM, tf1);
    wprep_kernel<<<(HDIM * EDIM + 255) / 256, 256, 0, stream>>>(Wf2, HDIM, EDIM, tf2);

    // 4. GIN layers
    for (int l = 0; l < NLAYERS; ++l) {
        gather_kernel<<<N_NODES / 4, 256, 0, stream>>>(h, row_ptr, eids, zin);
        for (long r0 = 0; r0 < N_NODES; r0 += chunk) {
            const int mc = (int)((N_NODES - r0 < chunk) ? (N_NODES - r0) : chunk);
            const int nrow1 = (mc + 127) / 128;
            // z2 = relu(zin @ W1[l] + b1[l])  [mc, 512] -> K-concat bf16 [mc][1024]
            gemm_mfma<2><<<4 * nrow1, 256, 0, stream>>>(
                zin + (size_t)r0 * 2 * HDIM, t1 + (size_t)l * T1SZ,
                b1 + (size_t)l * 2 * HDIM, nullptr, z2, mc, 2 * HDIM, 2 * HDIM);
            // h = relu(z2 @ W2[l] + b2[l])    [mc, 256] -> fp32
            gemm_mfma<1><<<2 * nrow1, 256, 0, stream>>>(
                z2, t2 + (size_t)l * T2SZ,
                b2 + (size_t)l * HDIM, h + (size_t)r0 * HDIM, nullptr, mc, HDIM, 4 * HDIM);
        }
    }

    // 5. pool (K-concat split write)
    pool_kernel<<<N_GRAPHS, HDIM, 0, stream>>>(h, batch, hg);

    // 6. head
    gemm_mfma<2><<<2 * ((N_GRAPHS + 127) / 128), 256, 0, stream>>>(
        hg, tf1, bf1, nullptr, hg1, N_GRAPHS, HDIM, 2 * HDIM);
    gemm_mfma<0><<<4 * ((N_GRAPHS + 127) / 128), 256, 0, stream>>>(
        hg1, tf2, bf2, out, nullptr, N_GRAPHS, EDIM, 2 * HDIM);
}

// Round 7
// 1597.158 us; speedup vs baseline: 3.9481x; 1.0524x over previous
//
#include <hip/hip_runtime.h>

#define N_NODES 100000
#define N_EDGES 200000
#define N_GRAPHS 4000
#define F_IN 44
#define HDIM 256
#define EDIM 512
#define NLAYERS 4

typedef float floatx4 __attribute__((ext_vector_type(4)));
typedef short bhalf8 __attribute__((ext_vector_type(8)));

__device__ __forceinline__ unsigned short f2bf(float f) {
    unsigned int u = __float_as_uint(f);
    u += 0x7FFFu + ((u >> 16) & 1u);          // RNE
    return (unsigned short)(u >> 16);
}
__device__ __forceinline__ float bf2f(unsigned short s) {
    return __uint_as_float(((unsigned int)s) << 16);
}
// packed (hi | lo<<16): ushort[2k]=hi, ushort[2k+1]=lo in little-endian memory
__device__ __forceinline__ unsigned int packbf(float v) {
    const unsigned short hh = f2bf(v);
    const unsigned short ll = f2bf(v - bf2f(hh));
    return (unsigned int)hh | ((unsigned int)ll << 16);
}

// async global->LDS, 16B/lane. ldst wave-uniform base; gsrc per-lane.
__device__ __forceinline__ void gload16(const void* gsrc, void* ldst) {
    __builtin_amdgcn_global_load_lds(
        (const __attribute__((address_space(1))) void*)gsrc,
        (__attribute__((address_space(3))) void*)ldst, 16, 0, 0);
}

// ---------------- zero fill ----------------
__global__ void zero_kernel(float* __restrict__ p, size_t n4) {
    size_t i = (size_t)blockIdx.x * blockDim.x + threadIdx.x;
    const size_t stride = (size_t)gridDim.x * blockDim.x;
    const float4 z = make_float4(0.f, 0.f, 0.f, 0.f);
    for (; i < n4; i += stride) ((float4*)p)[i] = z;
}

// -------- atom MLP: h = relu(x @ W_atom + b_atom). W resident in LDS, 8 nodes/group --------
__global__ __launch_bounds__(256) void atom_kernel(const float* __restrict__ x,
                                                   const float* __restrict__ W,
                                                   const float* __restrict__ b,
                                                   float* __restrict__ h) {
    __shared__ float ws[F_IN][HDIM];     // 45 KB
    __shared__ float xs[8 * F_IN];       // 1.4 KB
    const int t = threadIdx.x;
    for (int i = t; i < F_IN * HDIM; i += 256) ws[i / HDIM][i % HDIM] = W[i];
    const float bj = b[t];
    const int NG = N_NODES / 8;
    for (int g = blockIdx.x; g < NG; g += gridDim.x) {
        __syncthreads();                 // protect xs from previous iteration's readers
        for (int i = t; i < 8 * F_IN; i += 256) xs[i] = x[(size_t)g * 8 * F_IN + i];
        __syncthreads();
        float acc[8];
#pragma unroll
        for (int n = 0; n < 8; ++n) acc[n] = bj;
        for (int k = 0; k < F_IN; ++k) {
            const float w = ws[k][t];
#pragma unroll
            for (int n = 0; n < 8; ++n) acc[n] = fmaf(xs[n * F_IN + k], w, acc[n]);
        }
#pragma unroll
        for (int n = 0; n < 8; ++n)
            h[(size_t)(g * 8 + n) * HDIM + t] = fmaxf(acc[n], 0.f);
    }
}

// ---------------- CSR build ----------------
__global__ void hist_kernel(const int* __restrict__ dst, int* __restrict__ deg) {
    const int e = blockIdx.x * 256 + threadIdx.x;
    if (e < N_EDGES) atomicAdd(&deg[dst[e]], 1);
}

__global__ void scan1_kernel(const int* __restrict__ deg, int* __restrict__ row_ptr,
                             int* __restrict__ blk) {
    __shared__ int s[256];
    const int i = blockIdx.x * 256 + threadIdx.x;
    s[threadIdx.x] = (i < N_NODES) ? deg[i] : 0;
    __syncthreads();
    for (int off = 1; off < 256; off <<= 1) {
        int t = (threadIdx.x >= off) ? s[threadIdx.x - off] : 0;
        __syncthreads();
        s[threadIdx.x] += t;
        __syncthreads();
    }
    if (i < N_NODES) row_ptr[i + 1] = s[threadIdx.x];
    if (threadIdx.x == 255) blk[blockIdx.x] = s[255];
}

__global__ void scan2_kernel(int* __restrict__ blk, int nb) {
    if (threadIdx.x == 0 && blockIdx.x == 0) {
        int run = 0;
        for (int b = 0; b < nb; ++b) { const int t = blk[b]; blk[b] = run; run += t; }
    }
}

__global__ void scan3_kernel(int* __restrict__ row_ptr, const int* __restrict__ blk) {
    const int i = blockIdx.x * 256 + threadIdx.x;
    if (i < N_NODES) row_ptr[i + 1] += blk[i >> 8];
    if (i == 0) row_ptr[0] = 0;
}

__global__ void cursor_kernel(const int* __restrict__ row_ptr, int* __restrict__ cursor) {
    const int i = blockIdx.x * 256 + threadIdx.x;
    if (i < N_NODES) cursor[i] = row_ptr[i];
}

__global__ void fill_kernel(const int* __restrict__ src, const int* __restrict__ dst,
                            int* __restrict__ cursor, int* __restrict__ eids) {
    const int e = blockIdx.x * 256 + threadIdx.x;
    if (e < N_EDGES) {
        const int pos = atomicAdd(&cursor[dst[e]], 1);
        eids[pos] = src[e];
    }
}

// ------- gather: z = h + sum_neigh h; write K-interleaved hi/lo bf16 [n][2*HDIM] -------
__global__ void gather_kernel(const float* __restrict__ h, const int* __restrict__ row_ptr,
                              const int* __restrict__ eids, unsigned short* __restrict__ z) {
    const int tid = threadIdx.x;
    const int n = blockIdx.x * 4 + (tid >> 6);
    const int t = tid & 63;
    const float4* h4 = (const float4*)h;
    float4 acc = h4[(size_t)n * 64 + t];
    const int s = row_ptr[n], e = row_ptr[n + 1];
    for (int i = s; i < e; ++i) {
        const float4 v = h4[(size_t)eids[i] * 64 + t];
        acc.x += v.x; acc.y += v.y; acc.z += v.z; acc.w += v.w;
    }
    uint4 pk;
    pk.x = packbf(acc.x); pk.y = packbf(acc.y);
    pk.z = packbf(acc.z); pk.w = packbf(acc.w);
    ((uint4*)(z + (size_t)n * 2 * HDIM))[t] = pk;
}

// ------- weight prep: W[K][N] fp32 -> T[N][2K] bf16, K-interleaved (hi,lo) pairs -------
__global__ void wprep_kernel(const float* __restrict__ W, int K, int N,
                             unsigned short* __restrict__ T) {
    const int idx = blockIdx.x * 256 + threadIdx.x;
    if (idx < K * N) {
        const int k = idx / N, n = idx % N;
        ((unsigned int*)T)[(size_t)n * K + k] = packbf(W[idx]);
    }
}

// ---------------- MFMA GEMM: C = act(A @ B + bias), K-interleaved bf16 ----------------
// A [M][KK] bf16 row-major, BT [N][KK] bf16. KK multiple of 32.
// 128x128 tile, BK=32, 256 thr = 4 waves (2x2 of 64x64), 16 MFMA 16x16x32 per phase.
// Double-buffered LDS (4 x 8KB), counted s_waitcnt vmcnt(4), raw s_barrier (T3-min).
// LDS rows 64B, granule swizzle phys = g ^ ((row>>1)&3) -> 2-way max (free).
// OUT: 0 = fp32, 1 = fp32+relu, 2 = packed-uint hi/lo interleaved + relu
template <int OUT>
__global__ __launch_bounds__(256)
void gemm_mfma(const unsigned short* __restrict__ A, const unsigned short* __restrict__ BT,
               const float* __restrict__ bias, float* __restrict__ C,
               unsigned short* __restrict__ Z, int M, int N, int KK) {
    __shared__ __align__(16) unsigned short lds[4 * 4096];   // A0|B0|A1|B1, 32 KB

    const int nrow = (M + 127) >> 7;
    const int G = gridDim.x;
    int wg = blockIdx.x;
    {   // bijective XCD remap (m204)
        const int q = G >> 3, r = G & 7;
        const int xx = wg & 7, o = wg >> 3;
        wg = (xx < r ? xx * (q + 1) : r * (q + 1) + (xx - r) * q) + o;
    }
    const int row0 = (wg % nrow) << 7;
    const int col0 = (wg / nrow) << 7;

    const int tid = threadIdx.x;
    const int lane = tid & 63;
    const int w = tid >> 6;
    const int wr = w >> 1, wc = w & 1;
    const int lr = lane & 15;
    const int l4 = lane >> 4;

    // staging lane geometry: row = base + lane>>2, phys granule = lane&3
    const int lrow = lane >> 2;
    const int sgran = ((lane & 3) ^ ((lane >> 3) & 3)) << 3;   // pre-swizzled src granule
    // fragment read: swizzled granule for this lane
    const int pg = (l4 ^ ((lr >> 1) & 3)) << 3;

    floatx4 acc[4][4];
#pragma unroll
    for (int m = 0; m < 4; ++m)
#pragma unroll
        for (int n = 0; n < 4; ++n) acc[m][n] = (floatx4){0.f, 0.f, 0.f, 0.f};

    const int NT = KK >> 5;

    auto stage = [&](int t, int b) {
        const int k0 = t << 5;
        unsigned short* la = &lds[b * 8192];
        unsigned short* lb = &lds[b * 8192 + 4096];
#pragma unroll
        for (int j = 0; j < 2; ++j) {
            const int R = (w << 5) + (j << 4);          // wave-uniform row base
            int ar = row0 + R + lrow;
            if (ar >= M) ar = M - 1;                    // clamp (keeps vmcnt uniform)
            gload16(A + (size_t)ar * KK + k0 + sgran, la + (R << 5));
            gload16(BT + (size_t)(col0 + R + lrow) * KK + k0 + sgran, lb + (R << 5));
        }
    };

    stage(0, 0);
    int cur = 0;
    for (int t = 0; t < NT; ++t) {
        if (t + 1 < NT) {
            stage(t + 1, cur ^ 1);
            __builtin_amdgcn_sched_barrier(0);
            asm volatile("s_waitcnt vmcnt(4)" ::: "memory");   // tile t landed; t+1 in flight
        } else {
            __builtin_amdgcn_sched_barrier(0);
            asm volatile("s_waitcnt vmcnt(0)" ::: "memory");
        }
        __builtin_amdgcn_sched_barrier(0);
        __builtin_amdgcn_s_barrier();

        const unsigned short* la = &lds[cur * 8192];
        const unsigned short* lb = &lds[cur * 8192 + 4096];
        bhalf8 fa[4], fb[4];
#pragma unroll
        for (int m = 0; m < 4; ++m)
            fa[m] = *(const bhalf8*)&la[((wr << 6) + (m << 4) + lr) * 32 + pg];
#pragma unroll
        for (int n = 0; n < 4; ++n)
            fb[n] = *(const bhalf8*)&lb[((wc << 6) + (n << 4) + lr) * 32 + pg];
#pragma unroll
        for (int m = 0; m < 4; ++m)
#pragma unroll
            for (int n = 0; n < 4; ++n)
                acc[m][n] = __builtin_amdgcn_mfma_f32_16x16x32_bf16(fa[m], fb[n], acc[m][n], 0, 0, 0);

        __builtin_amdgcn_s_barrier();
        cur ^= 1;
    }

    // epilogue: C/D layout col = lane&15, row = (lane>>4)*4 + j
    const int rgrp = l4 * 4;
#pragma unroll
    for (int n = 0; n < 4; ++n) {
        const int col = col0 + wc * 64 + n * 16 + lr;
        const float bv = bias[col];
#pragma unroll
        for (int m = 0; m < 4; ++m) {
            const int rw = row0 + wr * 64 + m * 16 + rgrp;
#pragma unroll
            for (int j = 0; j < 4; ++j) {
                const int row = rw + j;
                if (row < M) {
                    float v = acc[m][n][j] + bv;
                    if (OUT >= 1) v = fmaxf(v, 0.f);
                    if (OUT == 2) {
                        ((unsigned int*)Z)[(size_t)row * N + col] = packbf(v);  // coalesced
                    } else {
                        C[(size_t)row * N + col] = v;
                    }
                }
            }
        }
    }
}

// ------- pool: sorted-batch segment mean -> K-interleaved hi/lo [g][2*HDIM] -------
__global__ void pool_kernel(const float* __restrict__ h, const int* __restrict__ batch,
                            unsigned short* __restrict__ gz) {
    __shared__ int sse[2];
    const int g = blockIdx.x;
    if (threadIdx.x < 2) {
        const int target = g + threadIdx.x;
        int lo = 0, hi = N_NODES;
        while (lo < hi) {
            const int mid = (lo + hi) >> 1;
            if (batch[mid] < target) lo = mid + 1; else hi = mid;
        }
        sse[threadIdx.x] = lo;
    }
    __syncthreads();
    const int s = sse[0], e = sse[1];
    const int j = threadIdx.x;
    float acc = 0.f;
    for (int n = s; n < e; ++n) acc += h[(size_t)n * HDIM + j];
    const float v = acc * ((e > s) ? 1.f / (float)(e - s) : 1.f);
    ((unsigned int*)gz)[(size_t)g * HDIM + j] = packbf(v);
}

extern "C" void kernel_launch(void* const* d_in, const int* in_sizes, int n_in,
                              void* d_out, int out_size, void* d_ws, size_t ws_size,
                              hipStream_t stream) {
    const float* x      = (const float*)d_in[0];
    const int*   eidx   = (const int*)d_in[1];
    const int*   batch  = (const int*)d_in[2];
    const float* W_atom = (const float*)d_in[3];
    const float* b_atom = (const float*)d_in[4];
    const float* W1     = (const float*)d_in[5];
    const float* b1     = (const float*)d_in[6];
    const float* W2     = (const float*)d_in[7];
    const float* b2     = (const float*)d_in[8];
    const float* Wf1    = (const float*)d_in[9];
    const float* bf1    = (const float*)d_in[10];
    const float* Wf2    = (const float*)d_in[11];
    const float* bf2    = (const float*)d_in[12];
    float* out = (float*)d_out;

    const int* src = eidx;
    const int* dst = eidx + N_EDGES;

    const size_t NH = (size_t)N_NODES * HDIM;           // 25.6M elems
    const int WSZ = HDIM * 2 * HDIM;                    // fp32 elems per layer weight

    // ---- workspace layout ----
    char* base = (char*)d_ws;
    size_t off = 0;
    float* h = (float*)(base + off);                        off += NH * 4;
    unsigned short* zin = (unsigned short*)(base + off);    off += NH * 2 * 2;  // [N][512]
    int* deg     = (int*)(base + off);            off += (size_t)N_NODES * 4;
    int* row_ptr = (int*)(base + off);            off += (size_t)(N_NODES + 1) * 4;
    int* cursor  = (int*)(base + off);            off += (size_t)N_NODES * 4;
    int* eids    = (int*)(base + off);            off += (size_t)N_EDGES * 4;
    int* blk     = (int*)(base + off);            off += 512 * 4;
    off = (off + 255) & ~(size_t)255;
    unsigned short* t1 = (unsigned short*)(base + off); off += (size_t)NLAYERS * WSZ * 2 * 2;
    unsigned short* t2 = (unsigned short*)(base + off); off += (size_t)NLAYERS * WSZ * 2 * 2;
    unsigned short* tf1 = (unsigned short*)(base + off); off += (size_t)HDIM * HDIM * 2 * 2;
    unsigned short* tf2 = (unsigned short*)(base + off); off += (size_t)HDIM * EDIM * 2 * 2;
    off = (off + 255) & ~(size_t)255;

    const size_t avail = (ws_size > off) ? ws_size - off : 0;
    long chunk = (long)(avail / ((size_t)EDIM * 2 * 2));   // z2 row = 2*EDIM ushorts
    if (chunk > 50048) chunk = 50048;                      // 2 chunks; z2 ~102MB L3-resident
    if (chunk >= N_NODES) chunk = N_NODES;
    else chunk &= ~127L;
    if (chunk < 128) chunk = 128;
    unsigned short* z2 = (unsigned short*)(base + off);    // [chunk][1024]

    // head buffers overlap the (dead-after-layers) zin region
    const size_t GH2 = (size_t)N_GRAPHS * 2 * HDIM;
    unsigned short* hg  = zin;            // [4000][512]
    unsigned short* hg1 = zin + GH2;      // [4000][512]

    const int nb = (N_NODES + 255) / 256;
    const int T1SZ = 2 * WSZ;
    const int T2SZ = 2 * WSZ;

    // 1. atom MLP (W in LDS, grid-stride groups of 8 nodes)
    atom_kernel<<<1563, 256, 0, stream>>>(x, W_atom, b_atom, h);

    // 2. CSR build
    zero_kernel<<<128, 256, 0, stream>>>((float*)deg, N_NODES / 4);
    hist_kernel<<<(N_EDGES + 255) / 256, 256, 0, stream>>>(dst, deg);
    scan1_kernel<<<nb, 256, 0, stream>>>(deg, row_ptr, blk);
    scan2_kernel<<<1, 64, 0, stream>>>(blk, nb);
    scan3_kernel<<<nb, 256, 0, stream>>>(row_ptr, blk);
    cursor_kernel<<<nb, 256, 0, stream>>>(row_ptr, cursor);
    fill_kernel<<<(N_EDGES + 255) / 256, 256, 0, stream>>>(src, dst, cursor, eids);

    // 3. weight transpose + K-interleaved bf16 split
    for (int l = 0; l < NLAYERS; ++l) {
        wprep_kernel<<<(WSZ + 255) / 256, 256, 0, stream>>>(
            W1 + (size_t)l * WSZ, HDIM, 2 * HDIM, t1 + (size_t)l * T1SZ);
        wprep_kernel<<<(WSZ + 255) / 256, 256, 0, stream>>>(
            W2 + (size_t)l * WSZ, 2 * HDIM, HDIM, t2 + (size_t)l * T2SZ);
    }
    wprep_kernel<<<(HDIM * HDIM + 255) / 256, 256, 0, stream>>>(Wf1, HDIM, HDIM, tf1);
    wprep_kernel<<<(HDIM * EDIM + 255) / 256, 256, 0, stream>>>(Wf2, HDIM, EDIM, tf2);

    // 4. GIN layers
    for (int l = 0; l < NLAYERS; ++l) {
        gather_kernel<<<N_NODES / 4, 256, 0, stream>>>(h, row_ptr, eids, zin);
        for (long r0 = 0; r0 < N_NODES; r0 += chunk) {
            const int mc = (int)((N_NODES - r0 < chunk) ? (N_NODES - r0) : chunk);
            const int nrow1 = (mc + 127) / 128;
            // z2 = relu(zin @ W1[l] + b1[l])  [mc, 512] -> interleaved bf16 [mc][1024]
            gemm_mfma<2><<<4 * nrow1, 256, 0, stream>>>(
                zin + (size_t)r0 * 2 * HDIM, t1 + (size_t)l * T1SZ,
                b1 + (size_t)l * 2 * HDIM, nullptr, z2, mc, 2 * HDIM, 2 * HDIM);
            // h = relu(z2 @ W2[l] + b2[l])    [mc, 256] -> fp32
            gemm_mfma<1><<<2 * nrow1, 256, 0, stream>>>(
                z2, t2 + (size_t)l * T2SZ,
                b2 + (size_t)l * HDIM, h + (size_t)r0 * HDIM, nullptr, mc, HDIM, 4 * HDIM);
        }
    }

    // 5. pool (interleaved split write)
    pool_kernel<<<N_GRAPHS, HDIM, 0, stream>>>(h, batch, hg);

    // 6. head
    gemm_mfma<2><<<2 * ((N_GRAPHS + 127) / 128), 256, 0, stream>>>(
        hg, tf1, bf1, nullptr, hg1, N_GRAPHS, HDIM, 2 * HDIM);
    gemm_mfma<0><<<4 * ((N_GRAPHS + 127) / 128), 256, 0, stream>>>(
        hg1, tf2, bf2, out, nullptr, N_GRAPHS, EDIM, 2 * HDIM);
}

// Round 8
// 1559.643 us; speedup vs baseline: 4.0430x; 1.0241x over previous
//
#include <hip/hip_runtime.h>

#define N_NODES 100000
#define N_EDGES 200000
#define N_GRAPHS 4000
#define F_IN 44
#define HDIM 256
#define EDIM 512
#define NLAYERS 4

typedef float floatx4 __attribute__((ext_vector_type(4)));
typedef short bhalf8 __attribute__((ext_vector_type(8)));

__device__ __forceinline__ unsigned short f2bf(float f) {
    unsigned int u = __float_as_uint(f);
    u += 0x7FFFu + ((u >> 16) & 1u);          // RNE
    return (unsigned short)(u >> 16);
}
__device__ __forceinline__ float bf2f(unsigned short s) {
    return __uint_as_float(((unsigned int)s) << 16);
}
// packed (hi | lo<<16): ushort[2k]=hi, ushort[2k+1]=lo in little-endian memory
__device__ __forceinline__ unsigned int packbf(float v) {
    const unsigned short hh = f2bf(v);
    const unsigned short ll = f2bf(v - bf2f(hh));
    return (unsigned int)hh | ((unsigned int)ll << 16);
}

// async global->LDS, 16B/lane. ldst wave-uniform base; gsrc per-lane.
__device__ __forceinline__ void gload16(const void* gsrc, void* ldst) {
    __builtin_amdgcn_global_load_lds(
        (const __attribute__((address_space(1))) void*)gsrc,
        (__attribute__((address_space(3))) void*)ldst, 16, 0, 0);
}

// ---------------- zero fill ----------------
__global__ void zero_kernel(float* __restrict__ p, size_t n4) {
    size_t i = (size_t)blockIdx.x * blockDim.x + threadIdx.x;
    const size_t stride = (size_t)gridDim.x * blockDim.x;
    const float4 z = make_float4(0.f, 0.f, 0.f, 0.f);
    for (; i < n4; i += stride) ((float4*)p)[i] = z;
}

// -------- atom MLP: h = relu(x @ W_atom + b_atom). W column in VGPRs, 8 nodes/group --------
__global__ __launch_bounds__(256) void atom_kernel(const float* __restrict__ x,
                                                   const float* __restrict__ W,
                                                   const float* __restrict__ b,
                                                   float* __restrict__ h) {
    const int t = threadIdx.x;
    float w[F_IN];
#pragma unroll
    for (int k = 0; k < F_IN; ++k) w[k] = W[k * HDIM + t];   // coalesced, once
    const float bj = b[t];
    __shared__ float xs[8 * F_IN];       // 1.4 KB broadcast buffer
    const int NG = N_NODES / 8;
    for (int g = blockIdx.x; g < NG; g += gridDim.x) {
        __syncthreads();                 // protect xs from previous readers
        for (int i = t; i < 8 * F_IN; i += 256) xs[i] = x[(size_t)g * 8 * F_IN + i];
        __syncthreads();
        float acc[8];
#pragma unroll
        for (int n = 0; n < 8; ++n) acc[n] = bj;
#pragma unroll
        for (int k = 0; k < F_IN; ++k) {
#pragma unroll
            for (int n = 0; n < 8; ++n) acc[n] = fmaf(xs[n * F_IN + k], w[k], acc[n]);
        }
#pragma unroll
        for (int n = 0; n < 8; ++n)
            h[(size_t)(g * 8 + n) * HDIM + t] = fmaxf(acc[n], 0.f);
    }
}

// ---------------- CSR build ----------------
__global__ void hist_kernel(const int* __restrict__ dst, int* __restrict__ deg) {
    const int e = blockIdx.x * 256 + threadIdx.x;
    if (e < N_EDGES) atomicAdd(&deg[dst[e]], 1);
}

__global__ void scan1_kernel(const int* __restrict__ deg, int* __restrict__ row_ptr,
                             int* __restrict__ blk) {
    __shared__ int s[256];
    const int i = blockIdx.x * 256 + threadIdx.x;
    s[threadIdx.x] = (i < N_NODES) ? deg[i] : 0;
    __syncthreads();
    for (int off = 1; off < 256; off <<= 1) {
        int t = (threadIdx.x >= off) ? s[threadIdx.x - off] : 0;
        __syncthreads();
        s[threadIdx.x] += t;
        __syncthreads();
    }
    if (i < N_NODES) row_ptr[i + 1] = s[threadIdx.x];
    if (threadIdx.x == 255) blk[blockIdx.x] = s[255];
}

__global__ void scan2_kernel(int* __restrict__ blk, int nb) {
    if (threadIdx.x == 0 && blockIdx.x == 0) {
        int run = 0;
        for (int b = 0; b < nb; ++b) { const int t = blk[b]; blk[b] = run; run += t; }
    }
}

__global__ void scan3_kernel(int* __restrict__ row_ptr, const int* __restrict__ blk) {
    const int i = blockIdx.x * 256 + threadIdx.x;
    if (i < N_NODES) row_ptr[i + 1] += blk[i >> 8];
    if (i == 0) row_ptr[0] = 0;
}

__global__ void cursor_kernel(const int* __restrict__ row_ptr, int* __restrict__ cursor) {
    const int i = blockIdx.x * 256 + threadIdx.x;
    if (i < N_NODES) cursor[i] = row_ptr[i];
}

__global__ void fill_kernel(const int* __restrict__ src, const int* __restrict__ dst,
                            int* __restrict__ cursor, int* __restrict__ eids) {
    const int e = blockIdx.x * 256 + threadIdx.x;
    if (e < N_EDGES) {
        const int pos = atomicAdd(&cursor[dst[e]], 1);
        eids[pos] = src[e];
    }
}

// ------- gather: z = h + sum_neigh h; write K-interleaved hi/lo bf16 [n][2*HDIM] -------
__global__ void gather_kernel(const float* __restrict__ h, const int* __restrict__ row_ptr,
                              const int* __restrict__ eids, unsigned short* __restrict__ z) {
    const int tid = threadIdx.x;
    const int n = blockIdx.x * 4 + (tid >> 6);
    const int t = tid & 63;
    const float4* h4 = (const float4*)h;
    float4 acc = h4[(size_t)n * 64 + t];
    const int s = row_ptr[n], e = row_ptr[n + 1];
    for (int i = s; i < e; ++i) {
        const float4 v = h4[(size_t)eids[i] * 64 + t];
        acc.x += v.x; acc.y += v.y; acc.z += v.z; acc.w += v.w;
    }
    uint4 pk;
    pk.x = packbf(acc.x); pk.y = packbf(acc.y);
    pk.z = packbf(acc.z); pk.w = packbf(acc.w);
    ((uint4*)(z + (size_t)n * 2 * HDIM))[t] = pk;
}

// ------- fused weight prep: all weights -> [N][K] packed (hi,lo)-uint, one dispatch -------
// W row-major [K][N] fp32 -> T as uint array [N][K], uint = hi | lo<<16.
__global__ void wprep_all(const float* __restrict__ W1, const float* __restrict__ W2,
                          const float* __restrict__ Wf1, const float* __restrict__ Wf2,
                          unsigned int* __restrict__ t1, unsigned int* __restrict__ t2,
                          unsigned int* __restrict__ tf1, unsigned int* __restrict__ tf2) {
    const int WSZ = HDIM * 2 * HDIM;                 // 131072
    const int total = 8 * WSZ + HDIM * HDIM + HDIM * EDIM;
    const int stride = gridDim.x * 256;
    for (int idx = blockIdx.x * 256 + threadIdx.x; idx < total; idx += stride) {
        if (idx < 4 * WSZ) {                         // W1: K=256, N=512
            const int l = idx >> 17, e = idx & (WSZ - 1);
            const int k = e >> 9, n = e & 511;
            t1[(size_t)l * WSZ + n * HDIM + k] = packbf(W1[idx]);
        } else if (idx < 8 * WSZ) {                  // W2: K=512, N=256
            const int r = idx - 4 * WSZ;
            const int l = r >> 17, e = r & (WSZ - 1);
            const int k = e >> 8, n = e & 255;
            t2[(size_t)l * WSZ + n * EDIM + k] = packbf(W2[r]);
        } else if (idx < 8 * WSZ + HDIM * HDIM) {    // Wf1: K=256, N=256
            const int e = idx - 8 * WSZ;
            const int k = e >> 8, n = e & 255;
            tf1[n * HDIM + k] = packbf(Wf1[e]);
        } else {                                     // Wf2: K=256, N=512
            const int e = idx - 8 * WSZ - HDIM * HDIM;
            const int k = e >> 9, n = e & 511;
            tf2[n * HDIM + k] = packbf(Wf2[e]);
        }
    }
}

// ---------------- MFMA GEMM: C = act(A @ B + bias), K-interleaved bf16 ----------------
// A [M][KK] bf16 row-major, BT [N][KK] bf16. KK multiple of 32, NT = KK/32 >= 2.
// 128x128 tile, BK=32, 256 thr = 4 waves (2x2 of 64x64), 16 MFMA 16x16x32 per phase.
// Ring-3 LDS (48 KB), depth-2 prefetch, counted s_waitcnt vmcnt(8) (never 0 mid-loop).
// LDS rows 64B, granule swizzle phys = g ^ ((row>>1)&3) -> 2-way max (free).
// OUT: 0 = fp32, 1 = fp32+relu, 2 = packed-uint hi/lo interleaved + relu
template <int OUT>
__global__ __launch_bounds__(256)
void gemm_mfma(const unsigned short* __restrict__ A, const unsigned short* __restrict__ BT,
               const float* __restrict__ bias, float* __restrict__ C,
               unsigned short* __restrict__ Z, int M, int N, int KK) {
    __shared__ __align__(16) unsigned short lds[3 * 8192];   // 3 x (A 8KB | B 8KB)

    const int nrow = (M + 127) >> 7;
    const int G = gridDim.x;
    int wg = blockIdx.x;
    {   // bijective XCD remap (m204)
        const int q = G >> 3, r = G & 7;
        const int xx = wg & 7, o = wg >> 3;
        wg = (xx < r ? xx * (q + 1) : r * (q + 1) + (xx - r) * q) + o;
    }
    const int row0 = (wg % nrow) << 7;
    const int col0 = (wg / nrow) << 7;

    const int tid = threadIdx.x;
    const int lane = tid & 63;
    const int w = tid >> 6;
    const int wr = w >> 1, wc = w & 1;
    const int lr = lane & 15;
    const int l4 = lane >> 4;

    // staging lane geometry: row = base + lane>>2, phys granule = lane&3
    const int lrow = lane >> 2;
    const int sgran = ((lane & 3) ^ ((lane >> 3) & 3)) << 3;   // pre-swizzled src granule
    // fragment read: swizzled granule for this lane
    const int pg = (l4 ^ ((lr >> 1) & 3)) << 3;

    floatx4 acc[4][4];
#pragma unroll
    for (int m = 0; m < 4; ++m)
#pragma unroll
        for (int n = 0; n < 4; ++n) acc[m][n] = (floatx4){0.f, 0.f, 0.f, 0.f};

    const int NT = KK >> 5;

    auto stage = [&](int t, int b) {
        const int k0 = t << 5;
        unsigned short* la = &lds[b * 8192];
        unsigned short* lb = la + 4096;
#pragma unroll
        for (int j = 0; j < 2; ++j) {
            const int R = (w << 5) + (j << 4);          // wave-uniform row base
            int ar = row0 + R + lrow;
            if (ar >= M) ar = M - 1;                    // clamp (keeps vmcnt uniform)
            gload16(A + (size_t)ar * KK + k0 + sgran, la + (R << 5));
            gload16(BT + (size_t)(col0 + R + lrow) * KK + k0 + sgran, lb + (R << 5));
        }
    };

    stage(0, 0);
    stage(1, 1);
    int rb = 0;                                        // read buffer = t % 3
    for (int t = 0; t < NT; ++t) {
        if (t + 2 < NT) {
            int wbuf = rb + 2; if (wbuf >= 3) wbuf -= 3;
            stage(t + 2, wbuf);                        // depth-2 prefetch
            __builtin_amdgcn_sched_barrier(0);
            asm volatile("s_waitcnt vmcnt(8)" ::: "memory");   // t landed; t+1,t+2 in flight
        } else if (t + 1 < NT) {
            __builtin_amdgcn_sched_barrier(0);
            asm volatile("s_waitcnt vmcnt(4)" ::: "memory");
        } else {
            __builtin_amdgcn_sched_barrier(0);
            asm volatile("s_waitcnt vmcnt(0)" ::: "memory");
        }
        __builtin_amdgcn_sched_barrier(0);
        __builtin_amdgcn_s_barrier();

        const unsigned short* la = &lds[rb * 8192];
        const unsigned short* lb = la + 4096;
        bhalf8 fa[4], fb[4];
#pragma unroll
        for (int m = 0; m < 4; ++m)
            fa[m] = *(const bhalf8*)&la[((wr << 6) + (m << 4) + lr) * 32 + pg];
#pragma unroll
        for (int n = 0; n < 4; ++n)
            fb[n] = *(const bhalf8*)&lb[((wc << 6) + (n << 4) + lr) * 32 + pg];
#pragma unroll
        for (int m = 0; m < 4; ++m)
#pragma unroll
            for (int n = 0; n < 4; ++n)
                acc[m][n] = __builtin_amdgcn_mfma_f32_16x16x32_bf16(fa[m], fb[n], acc[m][n], 0, 0, 0);

        asm volatile("s_waitcnt lgkmcnt(0)" ::: "memory");   // ds_reads done before reuse
        __builtin_amdgcn_sched_barrier(0);
        __builtin_amdgcn_s_barrier();
        rb = (rb + 1 == 3) ? 0 : rb + 1;
    }

    // epilogue: C/D layout col = lane&15, row = (lane>>4)*4 + j
    const int rgrp = l4 * 4;
#pragma unroll
    for (int n = 0; n < 4; ++n) {
        const int col = col0 + wc * 64 + n * 16 + lr;
        const float bv = bias[col];
#pragma unroll
        for (int m = 0; m < 4; ++m) {
            const int rw = row0 + wr * 64 + m * 16 + rgrp;
#pragma unroll
            for (int j = 0; j < 4; ++j) {
                const int row = rw + j;
                if (row < M) {
                    float v = acc[m][n][j] + bv;
                    if (OUT >= 1) v = fmaxf(v, 0.f);
                    if (OUT == 2) {
                        ((unsigned int*)Z)[(size_t)row * N + col] = packbf(v);  // coalesced
                    } else {
                        C[(size_t)row * N + col] = v;
                    }
                }
            }
        }
    }
}

// ------- pool: sorted-batch segment mean -> K-interleaved hi/lo [g][2*HDIM] -------
__global__ void pool_kernel(const float* __restrict__ h, const int* __restrict__ batch,
                            unsigned short* __restrict__ gz) {
    __shared__ int sse[2];
    const int g = blockIdx.x;
    if (threadIdx.x < 2) {
        const int target = g + threadIdx.x;
        int lo = 0, hi = N_NODES;
        while (lo < hi) {
            const int mid = (lo + hi) >> 1;
            if (batch[mid] < target) lo = mid + 1; else hi = mid;
        }
        sse[threadIdx.x] = lo;
    }
    __syncthreads();
    const int s = sse[0], e = sse[1];
    const int j = threadIdx.x;
    float acc = 0.f;
    for (int n = s; n < e; ++n) acc += h[(size_t)n * HDIM + j];
    const float v = acc * ((e > s) ? 1.f / (float)(e - s) : 1.f);
    ((unsigned int*)gz)[(size_t)g * HDIM + j] = packbf(v);
}

extern "C" void kernel_launch(void* const* d_in, const int* in_sizes, int n_in,
                              void* d_out, int out_size, void* d_ws, size_t ws_size,
                              hipStream_t stream) {
    const float* x      = (const float*)d_in[0];
    const int*   eidx   = (const int*)d_in[1];
    const int*   batch  = (const int*)d_in[2];
    const float* W_atom = (const float*)d_in[3];
    const float* b_atom = (const float*)d_in[4];
    const float* W1     = (const float*)d_in[5];
    const float* b1     = (const float*)d_in[6];
    const float* W2     = (const float*)d_in[7];
    const float* b2     = (const float*)d_in[8];
    const float* Wf1    = (const float*)d_in[9];
    const float* bf1    = (const float*)d_in[10];
    const float* Wf2    = (const float*)d_in[11];
    const float* bf2    = (const float*)d_in[12];
    float* out = (float*)d_out;

    const int* src = eidx;
    const int* dst = eidx + N_EDGES;

    const size_t NH = (size_t)N_NODES * HDIM;           // 25.6M elems
    const int WSZ = HDIM * 2 * HDIM;                    // fp32 elems per layer weight

    // ---- workspace layout ----
    char* base = (char*)d_ws;
    size_t off = 0;
    float* h = (float*)(base + off);                        off += NH * 4;
    unsigned short* zin = (unsigned short*)(base + off);    off += NH * 2 * 2;  // [N][512]
    int* deg     = (int*)(base + off);            off += (size_t)N_NODES * 4;
    int* row_ptr = (int*)(base + off);            off += (size_t)(N_NODES + 1) * 4;
    int* cursor  = (int*)(base + off);            off += (size_t)N_NODES * 4;
    int* eids    = (int*)(base + off);            off += (size_t)N_EDGES * 4;
    int* blk     = (int*)(base + off);            off += 512 * 4;
    off = (off + 255) & ~(size_t)255;
    unsigned short* t1 = (unsigned short*)(base + off); off += (size_t)NLAYERS * WSZ * 2 * 2;
    unsigned short* t2 = (unsigned short*)(base + off); off += (size_t)NLAYERS * WSZ * 2 * 2;
    unsigned short* tf1 = (unsigned short*)(base + off); off += (size_t)HDIM * HDIM * 2 * 2;
    unsigned short* tf2 = (unsigned short*)(base + off); off += (size_t)HDIM * EDIM * 2 * 2;
    off = (off + 255) & ~(size_t)255;

    const size_t avail = (ws_size > off) ? ws_size - off : 0;
    long chunk = (long)(avail / ((size_t)EDIM * 2 * 2));   // z2 row = 2*EDIM ushorts
    if (chunk > 50048) chunk = 50048;                      // 2 chunks; z2 L3-resident
    if (chunk >= N_NODES) chunk = N_NODES;
    else chunk &= ~127L;
    if (chunk < 128) chunk = 128;
    unsigned short* z2 = (unsigned short*)(base + off);    // [chunk][1024]

    // head buffers overlap the (dead-after-layers) zin region
    const size_t GH2 = (size_t)N_GRAPHS * 2 * HDIM;
    unsigned short* hg  = zin;            // [4000][512]
    unsigned short* hg1 = zin + GH2;      // [4000][512]

    const int nb = (N_NODES + 255) / 256;
    const int T1SZ = 2 * WSZ;
    const int T2SZ = 2 * WSZ;

    // 1. atom MLP (W in VGPRs, grid-stride groups of 8 nodes)
    atom_kernel<<<2048, 256, 0, stream>>>(x, W_atom, b_atom, h);

    // 2. CSR build
    zero_kernel<<<128, 256, 0, stream>>>((float*)deg, N_NODES / 4);
    hist_kernel<<<(N_EDGES + 255) / 256, 256, 0, stream>>>(dst, deg);
    scan1_kernel<<<nb, 256, 0, stream>>>(deg, row_ptr, blk);
    scan2_kernel<<<1, 64, 0, stream>>>(blk, nb);
    scan3_kernel<<<nb, 256, 0, stream>>>(row_ptr, blk);
    cursor_kernel<<<nb, 256, 0, stream>>>(row_ptr, cursor);
    fill_kernel<<<(N_EDGES + 255) / 256, 256, 0, stream>>>(src, dst, cursor, eids);

    // 3. fused weight transpose + K-interleaved bf16 split (one dispatch)
    wprep_all<<<1024, 256, 0, stream>>>(W1, W2, Wf1, Wf2,
        (unsigned int*)t1, (unsigned int*)t2, (unsigned int*)tf1, (unsigned int*)tf2);

    // 4. GIN layers
    for (int l = 0; l < NLAYERS; ++l) {
        gather_kernel<<<N_NODES / 4, 256, 0, stream>>>(h, row_ptr, eids, zin);
        for (long r0 = 0; r0 < N_NODES; r0 += chunk) {
            const int mc = (int)((N_NODES - r0 < chunk) ? (N_NODES - r0) : chunk);
            const int nrow1 = (mc + 127) / 128;
            // z2 = relu(zin @ W1[l] + b1[l])  [mc, 512] -> interleaved bf16 [mc][1024]
            gemm_mfma<2><<<4 * nrow1, 256, 0, stream>>>(
                zin + (size_t)r0 * 2 * HDIM, t1 + (size_t)l * T1SZ,
                b1 + (size_t)l * 2 * HDIM, nullptr, z2, mc, 2 * HDIM, 2 * HDIM);
            // h = relu(z2 @ W2[l] + b2[l])    [mc, 256] -> fp32
            gemm_mfma<1><<<2 * nrow1, 256, 0, stream>>>(
                z2, t2 + (size_t)l * T2SZ,
                b2 + (size_t)l * HDIM, h + (size_t)r0 * HDIM, nullptr, mc, HDIM, 4 * HDIM);
        }
    }

    // 5. pool (interleaved split write)
    pool_kernel<<<N_GRAPHS, HDIM, 0, stream>>>(h, batch, hg);

    // 6. head
    gemm_mfma<2><<<2 * ((N_GRAPHS + 127) / 128), 256, 0, stream>>>(
        hg, tf1, bf1, nullptr, hg1, N_GRAPHS, HDIM, 2 * HDIM);
    gemm_mfma<0><<<4 * ((N_GRAPHS + 127) / 128), 256, 0, stream>>>(
        hg1, tf2, bf2, out, nullptr, N_GRAPHS, EDIM, 2 * HDIM);
}